// Round 1
// baseline (568.438 us; speedup 1.0000x reference)
//
#include <hip/hip_runtime.h>
#include <cstdint>
#include <cstddef>

static constexpr int NN   = 20000;     // nodes
static constexpr int MPAD = 20096;     // 157 * 128
static constexpr int ERAW = 320000;    // given edges
static constexpr int ETOT = ERAW + NN; // + self loops

typedef __attribute__((ext_vector_type(8))) short bf16x8;
typedef __attribute__((ext_vector_type(4))) float f32x4;

__device__ __forceinline__ unsigned short f2bf(float f) {
  union { float f; unsigned u; } v; v.f = f;
  unsigned r = v.u + 0x7fffu + ((v.u >> 16) & 1u);
  return (unsigned short)(r >> 16);
}

__device__ __forceinline__ void gload_lds16(const void* g, void* l) {
  __builtin_amdgcn_global_load_lds(
      (const __attribute__((address_space(1))) unsigned int*)g,
      (__attribute__((address_space(3))) unsigned int*)l, 16, 0, 0);
}

// ---------------- conv1d (kernel==stride==24) -> h bf16 [MPAD][2048] ----------
// h[n, o*32+t] = sum_k x[n,k,t] * w[o,k] + b[o];  pad rows -> 0
__global__ __launch_bounds__(256) void conv_kernel(
    const float* __restrict__ x, const float* __restrict__ w,
    const float* __restrict__ b, unsigned short* __restrict__ h) {
  int n = blockIdx.x;
  int tid = threadIdx.x;
  size_t hrow = (size_t)n * 2048;
  if (n >= NN) {
#pragma unroll
    for (int i = 0; i < 8; i++) h[hrow + i * 256 + tid] = 0;
    return;
  }
  __shared__ float xs[768];
  __shared__ float ws[64 * 24];
  for (int i = tid; i < 768; i += 256) xs[i] = x[(size_t)n * 768 + i];
  for (int i = tid; i < 64 * 24; i += 256) ws[i] = w[i];
  __syncthreads();
  int t = tid & 31;
  int ob = tid >> 5;
  float xr[24];
#pragma unroll
  for (int k = 0; k < 24; k++) xr[k] = xs[k * 32 + t];
#pragma unroll
  for (int i = 0; i < 8; i++) {
    int o = ob + i * 8;                 // c = i*256+tid = o*32+t
    float acc = b[o];
#pragma unroll
    for (int k = 0; k < 24; k++) acc += xr[k] * ws[o * 24 + k];
    h[hrow + i * 256 + tid] = f2bf(acc);
  }
}

// ---------------- weight prep: W[k][n] (fp32) -> out[n][k] (bf16), n over [Wl|Wr]
__global__ __launch_bounds__(256) void wprep_kernel(
    const float* __restrict__ Wl, const float* __restrict__ Wr,
    unsigned short* __restrict__ out, int K, int nsplit) {
  __shared__ float tile[32][33];
  int kb = blockIdx.x * 32;
  int nb = blockIdx.y * 32;
  const float* W = (nb < nsplit) ? Wl : Wr;
  int nc = nb & (nsplit - 1);
  int tx = threadIdx.x & 31, ty = threadIdx.x >> 5;
#pragma unroll
  for (int i = 0; i < 4; i++)
    tile[ty + i * 8][tx] = W[(size_t)(kb + ty + i * 8) * nsplit + nc + tx];
  __syncthreads();
#pragma unroll
  for (int i = 0; i < 4; i++)
    out[(size_t)(nb + ty + i * 8) * K + kb + tx] = f2bf(tile[tx][ty + i * 8]);
}

// ---------------- bf16 MFMA GEMM: C[M][2*nsplit] = A[MPAD][K] * B^T[N][K] + bias
// 128x128 tile, BK=64, 4 waves (2x2), double-buffered global_load_lds staging.
__global__ __launch_bounds__(256, 2) void gemm_kernel(
    const unsigned short* __restrict__ A, const unsigned short* __restrict__ B,
    const float* __restrict__ bias0, const float* __restrict__ bias1,
    float* __restrict__ C0, float* __restrict__ C1,
    int M, int K, int NT, int nsplit) {
  __shared__ __align__(16) unsigned short As[2][128 * 64];
  __shared__ __align__(16) unsigned short Bs[2][128 * 64];
  int bid = blockIdx.x;
  int tm = bid / NT, tn = bid % NT;
  int tid = threadIdx.x, wid = tid >> 6, lane = tid & 63;
  int wr = wid >> 1, wc = wid & 1;
  const unsigned short* gA = A + (size_t)(tm * 128) * K;
  const unsigned short* gB = B + (size_t)(tn * 128) * K;
  int srow = wid * 8 + (lane >> 3);     // per-lane source row within tile
  int scol = (lane & 7) * 8;            // per-lane source col (elements)

  f32x4 acc[4][4];
  f32x4 zero = {0.f, 0.f, 0.f, 0.f};
#pragma unroll
  for (int i = 0; i < 4; i++)
#pragma unroll
    for (int j = 0; j < 4; j++) acc[i][j] = zero;

  auto stage = [&](int buf, int kt) {
    const unsigned short* a0 = gA + (size_t)srow * K + kt * 64 + scol;
    const unsigned short* b0 = gB + (size_t)srow * K + kt * 64 + scol;
#pragma unroll
    for (int i = 0; i < 4; i++)
      gload_lds16(a0 + (size_t)i * 32 * K, &As[buf][i * 2048 + wid * 512]);
#pragma unroll
    for (int i = 0; i < 4; i++)
      gload_lds16(b0 + (size_t)i * 32 * K, &Bs[buf][i * 2048 + wid * 512]);
  };

  auto compute = [&](int buf) {
#pragma unroll
    for (int kk = 0; kk < 2; kk++) {
      int ko = kk * 32 + (lane >> 4) * 8;
      bf16x8 af[4], bfr[4];
#pragma unroll
      for (int mi = 0; mi < 4; mi++)
        af[mi] = *(const bf16x8*)&As[buf][(wr * 64 + mi * 16 + (lane & 15)) * 64 + ko];
#pragma unroll
      for (int ni = 0; ni < 4; ni++)
        bfr[ni] = *(const bf16x8*)&Bs[buf][(wc * 64 + ni * 16 + (lane & 15)) * 64 + ko];
#pragma unroll
      for (int mi = 0; mi < 4; mi++)
#pragma unroll
        for (int ni = 0; ni < 4; ni++)
          acc[mi][ni] = __builtin_amdgcn_mfma_f32_16x16x32_bf16(
              af[mi], bfr[ni], acc[mi][ni], 0, 0, 0);
    }
  };

  int KT = K >> 6;
  stage(0, 0);
  asm volatile("s_waitcnt vmcnt(0)" ::: "memory");
  __syncthreads();
  int cur = 0;
  for (int kt = 1; kt < KT; ++kt) {
    stage(cur ^ 1, kt);
    compute(cur);
    asm volatile("s_waitcnt vmcnt(0)" ::: "memory");
    __syncthreads();
    cur ^= 1;
  }
  compute(cur);

  // epilogue: +bias, split columns into C0/C1, guard rows
  int ncol_tile = tn * 128;
  float* Cd; const float* bs; int col0;
  if (ncol_tile < nsplit) { Cd = C0; bs = bias0; col0 = ncol_tile; }
  else { Cd = C1; bs = bias1; col0 = ncol_tile - nsplit; }
#pragma unroll
  for (int mi = 0; mi < 4; mi++) {
    int rbase = tm * 128 + wr * 64 + mi * 16 + (lane >> 4) * 4;
#pragma unroll
    for (int ni = 0; ni < 4; ni++) {
      int c = col0 + wc * 64 + ni * 16 + (lane & 15);
      float bv = bs[c];
#pragma unroll
      for (int j = 0; j < 4; j++) {
        int r = rbase + j;
        if (r < M) Cd[(size_t)r * nsplit + c] = acc[mi][ni][j] + bv;
      }
    }
  }
}

// ---------------- CSR build ----------------
__global__ void deg_init_kernel(int* deg, int n) {
  int i = blockIdx.x * 256 + threadIdx.x;
  if (i < n) deg[i] = 1;  // self loop
}
__global__ void hist_kernel(const int* __restrict__ dst, int* deg, int E) {
  int e = blockIdx.x * 256 + threadIdx.x;
  if (e < E) atomicAdd(&deg[dst[e]], 1);
}
__global__ __launch_bounds__(1024) void scan_kernel(
    const int* __restrict__ deg, int* __restrict__ off, int* __restrict__ cursor, int n) {
  __shared__ int lds[1024];
  __shared__ int sbase;
  int tid = threadIdx.x;
  if (tid == 0) sbase = 0;
  __syncthreads();
  for (int chunk = 0; chunk < n; chunk += 1024) {
    int v = (chunk + tid < n) ? deg[chunk + tid] : 0;
    lds[tid] = v;
    __syncthreads();
    for (int d = 1; d < 1024; d <<= 1) {
      int t = (tid >= d) ? lds[tid - d] : 0;
      __syncthreads();
      lds[tid] += t;
      __syncthreads();
    }
    int excl = sbase + lds[tid] - v;
    if (chunk + tid < n) { off[chunk + tid] = excl; cursor[chunk + tid] = excl; }
    int tot = lds[1023];
    __syncthreads();
    if (tid == 0) sbase += tot;
    __syncthreads();
  }
  if (tid == 0) off[n] = sbase;
}
__global__ void scatter_kernel(const int* __restrict__ src, const int* __restrict__ dst,
                               int* cursor, int* __restrict__ esrc, int E, int n) {
  int e = blockIdx.x * 256 + threadIdx.x;
  if (e < E) {
    int d = dst[e];
    int pos = atomicAdd(&cursor[d], 1);
    esrc[pos] = src[e];
  } else if (e < E + n) {
    int i = e - E;
    int pos = atomicAdd(&cursor[i], 1);
    esrc[pos] = i;
  }
}

// ---------------- GATv2 aggregate: one wave per node, online softmax ----------
template <int VPL>
__global__ __launch_bounds__(256) void gat_agg_kernel(
    const float* __restrict__ xl, const float* __restrict__ xr,
    const float* __restrict__ att, const float* __restrict__ bias,
    const int* __restrict__ off, const int* __restrict__ esrc,
    float* __restrict__ out, int n, int do_relu) {
  constexpr int C = VPL * 64;
  int node = blockIdx.x * 4 + (threadIdx.x >> 6);
  if (node >= n) return;
  int lane = threadIdx.x & 63;
  int base = lane * VPL;
  float xrv[VPL], attv[VPL], acc[VPL];
#pragma unroll
  for (int v = 0; v < VPL; v++) {
    xrv[v] = xr[(size_t)node * C + base + v];
    attv[v] = att[base + v];
    acc[v] = 0.f;
  }
  float m = -1e30f, s = 0.f;
  int e0 = off[node], e1 = off[node + 1];
  for (int e = e0; e < e1; e++) {
    int sj = esrc[e];
    const float* xp = xl + (size_t)sj * C + base;
    float xlv[VPL];
    if constexpr (VPL == 8) {
      float4 a = *(const float4*)(xp);
      float4 b2 = *(const float4*)(xp + 4);
      xlv[0] = a.x; xlv[1] = a.y; xlv[2] = a.z; xlv[3] = a.w;
      xlv[4] = b2.x; xlv[5] = b2.y; xlv[6] = b2.z; xlv[7] = b2.w;
    } else {
      float2 a = *(const float2*)(xp);
      xlv[0] = a.x; xlv[1] = a.y;
    }
    float p = 0.f;
#pragma unroll
    for (int v = 0; v < VPL; v++) {
      float t = xlv[v] + xrv[v];
      t = t > 0.f ? t : 0.2f * t;   // leaky_relu(0.2)
      p += attv[v] * t;
    }
#pragma unroll
    for (int d2 = 32; d2; d2 >>= 1) p += __shfl_xor(p, d2);
    float mn = fmaxf(m, p);
    float scale = __expf(m - mn);
    float w = __expf(p - mn);
    s = s * scale + w;
#pragma unroll
    for (int v = 0; v < VPL; v++) acc[v] = acc[v] * scale + w * xlv[v];
    m = mn;
  }
  float inv = 1.f / (s + 1e-16f);
#pragma unroll
  for (int v = 0; v < VPL; v++) {
    float o = acc[v] * inv + bias[base + v];
    if (do_relu) o = fmaxf(o, 0.f);
    out[(size_t)node * C + base + v] = o;
  }
}

// ---------------- BatchNorm (training stats) ----------------
__global__ __launch_bounds__(256) void bn_stats_kernel(
    const float* __restrict__ h1, float* __restrict__ stats, int n) {
  int tid = threadIdx.x;
  int r0 = blockIdx.x * 128;
  int r1 = r0 + 128 < n ? r0 + 128 : n;
  float s0 = 0, s1 = 0, q0 = 0, q1 = 0;
  for (int r = r0; r < r1; ++r) {
    float a = h1[(size_t)r * 512 + tid];
    float b = h1[(size_t)r * 512 + tid + 256];
    s0 += a; q0 += a * a; s1 += b; q1 += b * b;
  }
  atomicAdd(&stats[tid], s0);
  atomicAdd(&stats[tid + 256], s1);
  atomicAdd(&stats[512 + tid], q0);
  atomicAdd(&stats[512 + tid + 256], q1);
}
__global__ __launch_bounds__(256) void bn_norm_kernel(
    const float* __restrict__ h1, const float* __restrict__ stats,
    const float* __restrict__ gamma, const float* __restrict__ beta,
    unsigned short* __restrict__ hbn, int n) {
  int idx = blockIdx.x * 256 + threadIdx.x;  // over MPAD*512
  int r = idx >> 9, c = idx & 511;
  if (r >= n) { hbn[idx] = 0; return; }
  float mean = stats[c] * (1.f / NN);
  float var = stats[512 + c] * (1.f / NN) - mean * mean;
  float invs = rsqrtf(var + 1e-5f);
  hbn[idx] = f2bf(gamma[c] * (h1[idx] - mean) * invs + beta[c]);
}

// ---------------- launch ----------------
extern "C" void kernel_launch(void* const* d_in, const int* in_sizes, int n_in,
                              void* d_out, int out_size, void* d_ws, size_t ws_size,
                              hipStream_t stream) {
  (void)in_sizes; (void)n_in; (void)out_size; (void)ws_size;
  const float* x      = (const float*)d_in[0];
  const int*   ei     = (const int*)d_in[1];
  const float* conv_w = (const float*)d_in[2];
  const float* conv_b = (const float*)d_in[3];
  const float* W1l    = (const float*)d_in[4];
  const float* b1l    = (const float*)d_in[5];
  const float* W1r    = (const float*)d_in[6];
  const float* b1r    = (const float*)d_in[7];
  const float* att1   = (const float*)d_in[8];
  const float* bias1  = (const float*)d_in[9];
  const float* gamma  = (const float*)d_in[10];
  const float* beta   = (const float*)d_in[11];
  const float* W2l    = (const float*)d_in[12];
  const float* b2l    = (const float*)d_in[13];
  const float* W2r    = (const float*)d_in[14];
  const float* b2r    = (const float*)d_in[15];
  const float* att2   = (const float*)d_in[16];
  const float* bias2  = (const float*)d_in[17];

  char* ws = (char*)d_ws;
  size_t off = 0;
  auto alloc = [&](size_t bytes) {
    size_t r = off;
    off += (bytes + 255) & ~(size_t)255;
    return r;
  };
  size_t o_h    = alloc((size_t)MPAD * 2048 * 2);  // bf16 h; reused for stage-2 bufs
  size_t o_wc1  = alloc((size_t)1024 * 2048 * 2);
  size_t o_wc2  = alloc((size_t)256 * 512 * 2);
  size_t o_xl1  = alloc((size_t)NN * 512 * 4);
  size_t o_xr1  = alloc((size_t)NN * 512 * 4);
  size_t o_off  = alloc((size_t)(NN + 1) * 4);
  size_t o_cur  = alloc((size_t)NN * 4);
  size_t o_deg  = alloc((size_t)NN * 4);
  size_t o_esrc = alloc((size_t)ETOT * 4);
  size_t o_stats = alloc((size_t)1024 * 4);

  unsigned short* h   = (unsigned short*)(ws + o_h);
  unsigned short* wc1 = (unsigned short*)(ws + o_wc1);
  unsigned short* wc2 = (unsigned short*)(ws + o_wc2);
  float* xl1 = (float*)(ws + o_xl1);
  float* xr1 = (float*)(ws + o_xr1);
  int* offp  = (int*)(ws + o_off);
  int* curp  = (int*)(ws + o_cur);
  int* degp  = (int*)(ws + o_deg);
  int* esrc  = (int*)(ws + o_esrc);
  float* stats = (float*)(ws + o_stats);
  // stage-2 buffers aliased into the (dead-after-GEMM1) h region:
  // h1 (fp32 20000x512 = 40,960,000 B) + hbn (bf16 20096x512 = 20,578,304 B)
  // + xl2/xr2 (fp32 20000x128 = 10,240,000 B each) = 82,018,304 <= 82,313,216
  float* h1 = (float*)(ws + o_h);
  unsigned short* hbn = (unsigned short*)(ws + o_h + 40960000);
  float* xl2 = (float*)(ws + o_h + 40960000 + 20578304);
  float* xr2 = (float*)(ws + o_h + 40960000 + 20578304 + 10240000);

  const int* src_raw = ei;
  const int* dst_raw = ei + ERAW;
  float* mu = (float*)d_out;

  hipMemsetAsync(stats, 0, 1024 * 4, stream);

  conv_kernel<<<MPAD, 256, 0, stream>>>(x, conv_w, conv_b, h);
  wprep_kernel<<<dim3(2048 / 32, 1024 / 32), 256, 0, stream>>>(W1l, W1r, wc1, 2048, 512);
  wprep_kernel<<<dim3(512 / 32, 256 / 32), 256, 0, stream>>>(W2l, W2r, wc2, 512, 128);

  // CSR build (independent of conv/gemm; stream-ordered anyway)
  deg_init_kernel<<<(NN + 255) / 256, 256, 0, stream>>>(degp, NN);
  hist_kernel<<<(ERAW + 255) / 256, 256, 0, stream>>>(dst_raw, degp, ERAW);
  scan_kernel<<<1, 1024, 0, stream>>>(degp, offp, curp, NN);
  scatter_kernel<<<(ETOT + 255) / 256, 256, 0, stream>>>(src_raw, dst_raw, curp, esrc, ERAW, NN);

  // layer 1
  gemm_kernel<<<(MPAD / 128) * (1024 / 128), 256, 0, stream>>>(
      h, wc1, b1l, b1r, xl1, xr1, NN, 2048, 8, 512);
  gat_agg_kernel<8><<<NN / 4, 256, 0, stream>>>(xl1, xr1, att1, bias1, offp, esrc, h1, NN, 1);

  // batchnorm
  bn_stats_kernel<<<(NN + 127) / 128, 256, 0, stream>>>(h1, stats, NN);
  bn_norm_kernel<<<(MPAD * 512) / 256, 256, 0, stream>>>(h1, stats, gamma, beta, hbn, NN);

  // layer 2
  gemm_kernel<<<(MPAD / 128) * (256 / 128), 256, 0, stream>>>(
      hbn, wc2, b2l, b2r, xl2, xr2, NN, 512, 2, 128);
  gat_agg_kernel<2><<<NN / 4, 256, 0, stream>>>(xl2, xr2, att2, bias2, offp, esrc, mu, NN, 0);
}

// Round 2
// 444.733 us; speedup vs baseline: 1.2782x; 1.2782x over previous
//
#include <hip/hip_runtime.h>
#include <cstdint>
#include <cstddef>

static constexpr int NN   = 20000;     // nodes
static constexpr int MPAD = 20096;     // 157 * 128
static constexpr int ERAW = 320000;    // given edges
static constexpr int ETOT = ERAW + NN; // + self loops

typedef __attribute__((ext_vector_type(8))) short bf16x8;
typedef __attribute__((ext_vector_type(4))) float f32x4;

__device__ __forceinline__ unsigned short f2bf(float f) {
  union { float f; unsigned u; } v; v.f = f;
  unsigned r = v.u + 0x7fffu + ((v.u >> 16) & 1u);
  return (unsigned short)(r >> 16);
}
__device__ __forceinline__ float bf2f(unsigned short u) {
  union { unsigned u; float f; } v; v.u = ((unsigned)u) << 16;
  return v.f;
}

__device__ __forceinline__ void gload_lds16(const void* g, void* l) {
  __builtin_amdgcn_global_load_lds(
      (const __attribute__((address_space(1))) unsigned int*)g,
      (__attribute__((address_space(3))) unsigned int*)l, 16, 0, 0);
}

// ---------------- conv1d (kernel==stride==24) -> h bf16 [MPAD][2048] ----------
__global__ __launch_bounds__(256) void conv_kernel(
    const float* __restrict__ x, const float* __restrict__ w,
    const float* __restrict__ b, unsigned short* __restrict__ h) {
  int n = blockIdx.x;
  int tid = threadIdx.x;
  size_t hrow = (size_t)n * 2048;
  if (n >= NN) {
#pragma unroll
    for (int i = 0; i < 8; i++) h[hrow + i * 256 + tid] = 0;
    return;
  }
  __shared__ float xs[768];
  __shared__ float ws[64 * 24];
  for (int i = tid; i < 768; i += 256) xs[i] = x[(size_t)n * 768 + i];
  for (int i = tid; i < 64 * 24; i += 256) ws[i] = w[i];
  __syncthreads();
  int t = tid & 31;
  int ob = tid >> 5;
  float xr[24];
#pragma unroll
  for (int k = 0; k < 24; k++) xr[k] = xs[k * 32 + t];
#pragma unroll
  for (int i = 0; i < 8; i++) {
    int o = ob + i * 8;                 // c = i*256+tid = o*32+t
    float acc = b[o];
#pragma unroll
    for (int k = 0; k < 24; k++) acc += xr[k] * ws[o * 24 + k];
    h[hrow + i * 256 + tid] = f2bf(acc);
  }
}

// ---------------- weight prep: W[k][n] (fp32) -> out[n][k] (bf16) -------------
__global__ __launch_bounds__(256) void wprep_kernel(
    const float* __restrict__ Wl, const float* __restrict__ Wr,
    unsigned short* __restrict__ out, int K, int nsplit) {
  __shared__ float tile[32][33];
  int kb = blockIdx.x * 32;
  int nb = blockIdx.y * 32;
  const float* W = (nb < nsplit) ? Wl : Wr;
  int nc = nb & (nsplit - 1);
  int tx = threadIdx.x & 31, ty = threadIdx.x >> 5;
#pragma unroll
  for (int i = 0; i < 4; i++)
    tile[ty + i * 8][tx] = W[(size_t)(kb + ty + i * 8) * nsplit + nc + tx];
  __syncthreads();
#pragma unroll
  for (int i = 0; i < 4; i++)
    out[(size_t)(nb + ty + i * 8) * K + kb + tx] = f2bf(tile[tx][ty + i * 8]);
}

// ---------------- bf16 MFMA GEMM (m97 structure: single-buffer, 2 barriers/K) -
// C[M][2*nsplit] = A[MPAD][K] * B^T[N][K] + bias; 128x128 tile, BK=64, 4 waves.
template <typename OutT>
__global__ __launch_bounds__(256, 5) void gemm_kernel(
    const unsigned short* __restrict__ A, const unsigned short* __restrict__ B,
    const float* __restrict__ bias0, const float* __restrict__ bias1,
    OutT* __restrict__ C0, OutT* __restrict__ C1,
    int M, int K, int NT, int nsplit, int swz) {
  __shared__ __align__(16) unsigned short As[128 * 64];
  __shared__ __align__(16) unsigned short Bs[128 * 64];
  int bid = blockIdx.x;
  if (swz) bid = (bid & 7) * (gridDim.x >> 3) + (bid >> 3);  // XCD-chunked (nwg%8==0)
  int tm = bid / NT, tn = bid % NT;
  int tid = threadIdx.x, wid = tid >> 6, lane = tid & 63;
  int wr = wid >> 1, wc = wid & 1;
  const unsigned short* gA = A + (size_t)(tm * 128) * K;
  const unsigned short* gB = B + (size_t)(tn * 128) * K;
  int srow = wid * 8 + (lane >> 3);
  int scol = (lane & 7) * 8;

  f32x4 acc[4][4];
  f32x4 zero = {0.f, 0.f, 0.f, 0.f};
#pragma unroll
  for (int i = 0; i < 4; i++)
#pragma unroll
    for (int j = 0; j < 4; j++) acc[i][j] = zero;

  int KT = K >> 6;
  for (int kt = 0; kt < KT; ++kt) {
    if (kt) __syncthreads();            // prior compute done with LDS
    {
      const unsigned short* a0 = gA + (size_t)srow * K + kt * 64 + scol;
      const unsigned short* b0 = gB + (size_t)srow * K + kt * 64 + scol;
#pragma unroll
      for (int i = 0; i < 4; i++)
        gload_lds16(a0 + (size_t)i * 32 * K, &As[i * 2048 + wid * 512]);
#pragma unroll
      for (int i = 0; i < 4; i++)
        gload_lds16(b0 + (size_t)i * 32 * K, &Bs[i * 2048 + wid * 512]);
    }
    asm volatile("s_waitcnt vmcnt(0)" ::: "memory");
    __syncthreads();
#pragma unroll
    for (int kk = 0; kk < 2; kk++) {
      int ko = kk * 32 + (lane >> 4) * 8;
      bf16x8 af[4], bfr[4];
#pragma unroll
      for (int mi = 0; mi < 4; mi++)
        af[mi] = *(const bf16x8*)&As[(wr * 64 + mi * 16 + (lane & 15)) * 64 + ko];
#pragma unroll
      for (int ni = 0; ni < 4; ni++)
        bfr[ni] = *(const bf16x8*)&Bs[(wc * 64 + ni * 16 + (lane & 15)) * 64 + ko];
#pragma unroll
      for (int mi = 0; mi < 4; mi++)
#pragma unroll
        for (int ni = 0; ni < 4; ni++)
          acc[mi][ni] = __builtin_amdgcn_mfma_f32_16x16x32_bf16(
              af[mi], bfr[ni], acc[mi][ni], 0, 0, 0);
    }
  }

  // epilogue: +bias, split columns into C0/C1, guard rows
  int ncol_tile = tn * 128;
  OutT* Cd; const float* bs; int col0;
  if (ncol_tile < nsplit) { Cd = C0; bs = bias0; col0 = ncol_tile; }
  else { Cd = C1; bs = bias1; col0 = ncol_tile - nsplit; }
#pragma unroll
  for (int mi = 0; mi < 4; mi++) {
    int rbase = tm * 128 + wr * 64 + mi * 16 + (lane >> 4) * 4;
#pragma unroll
    for (int ni = 0; ni < 4; ni++) {
      int c = col0 + wc * 64 + ni * 16 + (lane & 15);
      float bv = bs[c];
#pragma unroll
      for (int j = 0; j < 4; j++) {
        int r = rbase + j;
        if (r < M) {
          float v = acc[mi][ni][j] + bv;
          if constexpr (sizeof(OutT) == 2) Cd[(size_t)r * nsplit + c] = f2bf(v);
          else Cd[(size_t)r * nsplit + c] = v;
        }
      }
    }
  }
}

// ---------------- CSR build ----------------
__global__ void deg_init_kernel(int* deg, int n) {
  int i = blockIdx.x * 256 + threadIdx.x;
  if (i < n) deg[i] = 1;  // self loop
}
__global__ void hist_kernel(const int* __restrict__ dst, int* deg, int E) {
  int e = blockIdx.x * 256 + threadIdx.x;
  if (e < E) atomicAdd(&deg[dst[e]], 1);
}
__global__ __launch_bounds__(1024) void scan_kernel(
    const int* __restrict__ deg, int* __restrict__ off, int* __restrict__ cursor, int n) {
  __shared__ int wsum[16];
  __shared__ int sbase;
  int tid = threadIdx.x, lane = tid & 63, w = tid >> 6;
  if (tid == 0) sbase = 0;
  __syncthreads();
  for (int chunk = 0; chunk < n; chunk += 1024) {
    int i = chunk + tid;
    int v = (i < n) ? deg[i] : 0;
    int s = v;                               // inclusive wave scan
#pragma unroll
    for (int d = 1; d < 64; d <<= 1) {
      int t = __shfl_up(s, d);
      if (lane >= d) s += t;
    }
    if (lane == 63) wsum[w] = s;
    __syncthreads();
    if (w == 0 && lane < 16) {
      int t = wsum[lane];
#pragma unroll
      for (int d = 1; d < 16; d <<= 1) {
        int u = __shfl_up(t, d);
        if (lane >= d) t += u;
      }
      wsum[lane] = t;
    }
    __syncthreads();
    int excl = sbase + (w ? wsum[w - 1] : 0) + s - v;
    if (i < n) { off[i] = excl; cursor[i] = excl; }
    int tot = wsum[15];
    __syncthreads();
    if (tid == 0) sbase += tot;
    __syncthreads();
  }
  if (tid == 0) off[n] = sbase;
}
__global__ void scatter_kernel(const int* __restrict__ src, const int* __restrict__ dst,
                               int* cursor, int* __restrict__ esrc, int E, int n) {
  int e = blockIdx.x * 256 + threadIdx.x;
  if (e < E) {
    int d = dst[e];
    int pos = atomicAdd(&cursor[d], 1);
    esrc[pos] = src[e];
  } else if (e < E + n) {
    int i = e - E;
    int pos = atomicAdd(&cursor[i], 1);
    esrc[pos] = i;
  }
}

// ---------------- GATv2 aggregate: one wave per node, online softmax ----------
// T = unsigned short (bf16 features) or float
template <int VPL, typename T>
__global__ __launch_bounds__(256) void gat_agg_kernel(
    const T* __restrict__ xl, const T* __restrict__ xr,
    const float* __restrict__ att, const float* __restrict__ bias,
    const int* __restrict__ off, const int* __restrict__ esrc,
    float* __restrict__ out, int n, int do_relu) {
  constexpr int C = VPL * 64;
  int node = blockIdx.x * 4 + (threadIdx.x >> 6);
  if (node >= n) return;
  int lane = threadIdx.x & 63;
  int base = lane * VPL;
  float xrv[VPL], attv[VPL], acc[VPL];
#pragma unroll
  for (int v = 0; v < VPL; v++) {
    if constexpr (sizeof(T) == 2) xrv[v] = bf2f(xr[(size_t)node * C + base + v]);
    else xrv[v] = xr[(size_t)node * C + base + v];
    attv[v] = att[base + v];
    acc[v] = 0.f;
  }
  float m = -1e30f, s = 0.f;
  int e0 = off[node], e1 = off[node + 1];
  for (int e = e0; e < e1; e++) {
    int sj = esrc[e];
    const T* xp = xl + (size_t)sj * C + base;
    float xlv[VPL];
    if constexpr (sizeof(T) == 2) {
      if constexpr (VPL == 8) {
        bf16x8 raw = *(const bf16x8*)xp;   // one 16B load
#pragma unroll
        for (int v = 0; v < 8; v++) xlv[v] = bf2f((unsigned short)raw[v]);
      } else {
        uint r = *(const uint*)xp;
        xlv[0] = bf2f((unsigned short)(r & 0xffff));
        xlv[1] = bf2f((unsigned short)(r >> 16));
      }
    } else {
      if constexpr (VPL == 8) {
        float4 a = *(const float4*)(xp);
        float4 b2 = *(const float4*)(xp + 4);
        xlv[0] = a.x; xlv[1] = a.y; xlv[2] = a.z; xlv[3] = a.w;
        xlv[4] = b2.x; xlv[5] = b2.y; xlv[6] = b2.z; xlv[7] = b2.w;
      } else {
        float2 a = *(const float2*)(xp);
        xlv[0] = a.x; xlv[1] = a.y;
      }
    }
    float p = 0.f;
#pragma unroll
    for (int v = 0; v < VPL; v++) {
      float t = xlv[v] + xrv[v];
      t = t > 0.f ? t : 0.2f * t;   // leaky_relu(0.2)
      p += attv[v] * t;
    }
#pragma unroll
    for (int d2 = 32; d2; d2 >>= 1) p += __shfl_xor(p, d2);
    float mn = fmaxf(m, p);
    float scale = __expf(m - mn);
    float w = __expf(p - mn);
    s = s * scale + w;
#pragma unroll
    for (int v = 0; v < VPL; v++) acc[v] = acc[v] * scale + w * xlv[v];
    m = mn;
  }
  float inv = 1.f / (s + 1e-16f);
#pragma unroll
  for (int v = 0; v < VPL; v++) {
    float o = acc[v] * inv + bias[base + v];
    if (do_relu) o = fmaxf(o, 0.f);
    out[(size_t)node * C + base + v] = o;
  }
}

// ---------------- BatchNorm (training stats) ----------------
__global__ __launch_bounds__(256) void bn_stats_kernel(
    const float* __restrict__ h1, float* __restrict__ stats, int n) {
  int tid = threadIdx.x;
  int r0 = blockIdx.x * 128;
  int r1 = r0 + 128 < n ? r0 + 128 : n;
  float s0 = 0, s1 = 0, q0 = 0, q1 = 0;
  for (int r = r0; r < r1; ++r) {
    float a = h1[(size_t)r * 512 + tid];
    float b = h1[(size_t)r * 512 + tid + 256];
    s0 += a; q0 += a * a; s1 += b; q1 += b * b;
  }
  atomicAdd(&stats[tid], s0);
  atomicAdd(&stats[tid + 256], s1);
  atomicAdd(&stats[512 + tid], q0);
  atomicAdd(&stats[512 + tid + 256], q1);
}
__global__ __launch_bounds__(256) void bn_norm_kernel(
    const float* __restrict__ h1, const float* __restrict__ stats,
    const float* __restrict__ gamma, const float* __restrict__ beta,
    unsigned short* __restrict__ hbn, int n) {
  int idx = blockIdx.x * 256 + threadIdx.x;  // over MPAD*512
  int r = idx >> 9, c = idx & 511;
  if (r >= n) { hbn[idx] = 0; return; }
  float mean = stats[c] * (1.f / NN);
  float var = stats[512 + c] * (1.f / NN) - mean * mean;
  float invs = rsqrtf(var + 1e-5f);
  hbn[idx] = f2bf(gamma[c] * (h1[idx] - mean) * invs + beta[c]);
}

// ---------------- launch ----------------
extern "C" void kernel_launch(void* const* d_in, const int* in_sizes, int n_in,
                              void* d_out, int out_size, void* d_ws, size_t ws_size,
                              hipStream_t stream) {
  (void)in_sizes; (void)n_in; (void)out_size; (void)ws_size;
  const float* x      = (const float*)d_in[0];
  const int*   ei     = (const int*)d_in[1];
  const float* conv_w = (const float*)d_in[2];
  const float* conv_b = (const float*)d_in[3];
  const float* W1l    = (const float*)d_in[4];
  const float* b1l    = (const float*)d_in[5];
  const float* W1r    = (const float*)d_in[6];
  const float* b1r    = (const float*)d_in[7];
  const float* att1   = (const float*)d_in[8];
  const float* bias1  = (const float*)d_in[9];
  const float* gamma  = (const float*)d_in[10];
  const float* beta   = (const float*)d_in[11];
  const float* W2l    = (const float*)d_in[12];
  const float* b2l    = (const float*)d_in[13];
  const float* W2r    = (const float*)d_in[14];
  const float* b2r    = (const float*)d_in[15];
  const float* att2   = (const float*)d_in[16];
  const float* bias2  = (const float*)d_in[17];

  char* ws = (char*)d_ws;
  size_t off = 0;
  auto alloc = [&](size_t bytes) {
    size_t r = off;
    off += (bytes + 255) & ~(size_t)255;
    return r;
  };
  size_t o_h    = alloc((size_t)MPAD * 2048 * 2);  // bf16 h; reused for stage-2 bufs
  size_t o_wc1  = alloc((size_t)1024 * 2048 * 2);
  size_t o_wc2  = alloc((size_t)256 * 512 * 2);
  size_t o_xl1  = alloc((size_t)NN * 512 * 2);     // bf16 now
  size_t o_xr1  = alloc((size_t)NN * 512 * 2);
  size_t o_off  = alloc((size_t)(NN + 1) * 4);
  size_t o_cur  = alloc((size_t)NN * 4);
  size_t o_deg  = alloc((size_t)NN * 4);
  size_t o_esrc = alloc((size_t)ETOT * 4);
  size_t o_stats = alloc((size_t)1024 * 4);

  unsigned short* h   = (unsigned short*)(ws + o_h);
  unsigned short* wc1 = (unsigned short*)(ws + o_wc1);
  unsigned short* wc2 = (unsigned short*)(ws + o_wc2);
  unsigned short* xl1 = (unsigned short*)(ws + o_xl1);
  unsigned short* xr1 = (unsigned short*)(ws + o_xr1);
  int* offp  = (int*)(ws + o_off);
  int* curp  = (int*)(ws + o_cur);
  int* degp  = (int*)(ws + o_deg);
  int* esrc  = (int*)(ws + o_esrc);
  float* stats = (float*)(ws + o_stats);
  // stage-2 buffers aliased into the (dead-after-GEMM1) h region:
  float* h1 = (float*)(ws + o_h);                              // 40,960,000 B
  unsigned short* hbn = (unsigned short*)(ws + o_h + 40960000);// 20,578,304 B
  float* xl2 = (float*)(ws + o_h + 40960000 + 20578304);       // 10,240,000 B
  float* xr2 = (float*)(ws + o_h + 40960000 + 20578304 + 10240000);

  const int* src_raw = ei;
  const int* dst_raw = ei + ERAW;
  float* mu = (float*)d_out;

  hipMemsetAsync(stats, 0, 1024 * 4, stream);

  conv_kernel<<<MPAD, 256, 0, stream>>>(x, conv_w, conv_b, h);
  wprep_kernel<<<dim3(2048 / 32, 1024 / 32), 256, 0, stream>>>(W1l, W1r, wc1, 2048, 512);
  wprep_kernel<<<dim3(512 / 32, 256 / 32), 256, 0, stream>>>(W2l, W2r, wc2, 512, 128);

  deg_init_kernel<<<(NN + 255) / 256, 256, 0, stream>>>(degp, NN);
  hist_kernel<<<(ERAW + 255) / 256, 256, 0, stream>>>(dst_raw, degp, ERAW);
  scan_kernel<<<1, 1024, 0, stream>>>(degp, offp, curp, NN);
  scatter_kernel<<<(ETOT + 255) / 256, 256, 0, stream>>>(src_raw, dst_raw, curp, esrc, ERAW, NN);

  // layer 1 (bf16 xl/xr for the gather)
  gemm_kernel<unsigned short><<<(MPAD / 128) * (1024 / 128), 256, 0, stream>>>(
      h, wc1, b1l, b1r, xl1, xr1, NN, 2048, 8, 512, 1);
  gat_agg_kernel<8, unsigned short><<<NN / 4, 256, 0, stream>>>(
      xl1, xr1, att1, bias1, offp, esrc, h1, NN, 1);

  // batchnorm
  bn_stats_kernel<<<(NN + 127) / 128, 256, 0, stream>>>(h1, stats, NN);
  bn_norm_kernel<<<(MPAD * 512) / 256, 256, 0, stream>>>(h1, stats, gamma, beta, hbn, NN);

  // layer 2 (fp32 to protect final output precision)
  gemm_kernel<float><<<(MPAD / 128) * (256 / 128), 256, 0, stream>>>(
      hbn, wc2, b2l, b2r, xl2, xr2, NN, 512, 2, 128, 0);
  gat_agg_kernel<2, float><<<NN / 4, 256, 0, stream>>>(
      xl2, xr2, att2, bias2, offp, esrc, mu, NN, 0);
}

// Round 3
// 383.609 us; speedup vs baseline: 1.4818x; 1.1593x over previous
//
#include <hip/hip_runtime.h>
#include <cstdint>
#include <cstddef>
#include <type_traits>

static constexpr int NN   = 20000;     // nodes
static constexpr int MPAD = 20096;     // 157 * 128
static constexpr int ERAW = 320000;    // given edges
static constexpr int ETOT = ERAW + NN; // + self loops

typedef __attribute__((ext_vector_type(8))) short bf16x8;
typedef __attribute__((ext_vector_type(4))) float f32x4;

__device__ __forceinline__ unsigned short f2bf(float f) {
  union { float f; unsigned u; } v; v.f = f;
  unsigned r = v.u + 0x7fffu + ((v.u >> 16) & 1u);
  return (unsigned short)(r >> 16);
}
__device__ __forceinline__ float bf2f(unsigned short u) {
  union { unsigned u; float f; } v; v.u = ((unsigned)u) << 16;
  return v.f;
}

__device__ __forceinline__ void gload_lds16(const void* g, void* l) {
  __builtin_amdgcn_global_load_lds(
      (const __attribute__((address_space(1))) unsigned int*)g,
      (__attribute__((address_space(3))) unsigned int*)l, 16, 0, 0);
}

// ---------------- conv1d (kernel==stride==24) -> h bf16 [MPAD][2048] ----------
__global__ __launch_bounds__(256) void conv_kernel(
    const float* __restrict__ x, const float* __restrict__ w,
    const float* __restrict__ b, unsigned short* __restrict__ h) {
  int n = blockIdx.x;
  int tid = threadIdx.x;
  size_t hrow = (size_t)n * 2048;
  if (n >= NN) {
#pragma unroll
    for (int i = 0; i < 8; i++) h[hrow + i * 256 + tid] = 0;
    return;
  }
  __shared__ float xs[768];
  __shared__ float ws[64 * 24];
  for (int i = tid; i < 768; i += 256) xs[i] = x[(size_t)n * 768 + i];
  for (int i = tid; i < 64 * 24; i += 256) ws[i] = w[i];
  __syncthreads();
  int t = tid & 31;
  int ob = tid >> 5;
  float xr[24];
#pragma unroll
  for (int k = 0; k < 24; k++) xr[k] = xs[k * 32 + t];
#pragma unroll
  for (int i = 0; i < 8; i++) {
    int o = ob + i * 8;                 // c = i*256+tid = o*32+t
    float acc = b[o];
#pragma unroll
    for (int k = 0; k < 24; k++) acc += xr[k] * ws[o * 24 + k];
    h[hrow + i * 256 + tid] = f2bf(acc);
  }
}

// ---------------- weight prep: W[k][n] (fp32) -> out[n][k] (bf16) -------------
__global__ __launch_bounds__(256) void wprep_kernel(
    const float* __restrict__ Wl, const float* __restrict__ Wr,
    unsigned short* __restrict__ out, int K, int nsplit) {
  __shared__ float tile[32][33];
  int kb = blockIdx.x * 32;
  int nb = blockIdx.y * 32;
  const float* W = (nb < nsplit) ? Wl : Wr;
  int nc = nb & (nsplit - 1);
  int tx = threadIdx.x & 31, ty = threadIdx.x >> 5;
#pragma unroll
  for (int i = 0; i < 4; i++)
    tile[ty + i * 8][tx] = W[(size_t)(kb + ty + i * 8) * nsplit + nc + tx];
  __syncthreads();
#pragma unroll
  for (int i = 0; i < 4; i++)
    out[(size_t)(nb + ty + i * 8) * K + kb + tx] = f2bf(tile[tx][ty + i * 8]);
}

// ---------------- bf16 MFMA GEMM (m97 2-phase + T2 swizzle) -------------------
// C[M][2*nsplit] = A[MPAD][K] * B^T[N][K] + bias; 128x128 tile, BK=64, 4 waves.
// T2 per rule 21: linear gload_lds dest + inverse-swizzled per-lane GLOBAL src
// + swizzled ds_read col. LDS[r][slot s] holds G[r][s ^ (r&7)] (16B slots).
template <typename OutT>
__global__ __launch_bounds__(256, 5) void gemm_kernel(
    const unsigned short* __restrict__ A, const unsigned short* __restrict__ B,
    const float* __restrict__ bias0, const float* __restrict__ bias1,
    OutT* __restrict__ C0, OutT* __restrict__ C1,
    int M, int K, int NT, int nsplit, int swz) {
  __shared__ __align__(16) unsigned short As[128 * 64];
  __shared__ __align__(16) unsigned short Bs[128 * 64];
  int bid = blockIdx.x;
  if (swz) bid = (bid & 7) * (gridDim.x >> 3) + (bid >> 3);  // XCD-chunked (nwg%8==0)
  int tm = bid / NT, tn = bid % NT;
  int tid = threadIdx.x, wid = tid >> 6, lane = tid & 63;
  int wr = wid >> 1, wc = wid & 1;
  const unsigned short* gA = A + (size_t)(tm * 128) * K;
  const unsigned short* gB = B + (size_t)(tn * 128) * K;
  int srow = wid * 8 + (lane >> 3);
  int scol = ((lane & 7) ^ (lane >> 3)) * 8;   // T2: srow&7 == lane>>3

  f32x4 acc[4][4];
  f32x4 zero = {0.f, 0.f, 0.f, 0.f};
#pragma unroll
  for (int i = 0; i < 4; i++)
#pragma unroll
    for (int j = 0; j < 4; j++) acc[i][j] = zero;

  int KT = K >> 6;
  for (int kt = 0; kt < KT; ++kt) {
    if (kt) __syncthreads();            // prior compute done with LDS
    {
      const unsigned short* a0 = gA + (size_t)srow * K + kt * 64 + scol;
      const unsigned short* b0 = gB + (size_t)srow * K + kt * 64 + scol;
#pragma unroll
      for (int i = 0; i < 4; i++)
        gload_lds16(a0 + (size_t)i * 32 * K, &As[i * 2048 + wid * 512]);
#pragma unroll
      for (int i = 0; i < 4; i++)
        gload_lds16(b0 + (size_t)i * 32 * K, &Bs[i * 2048 + wid * 512]);
    }
    asm volatile("s_waitcnt vmcnt(0)" ::: "memory");
    __syncthreads();
#pragma unroll
    for (int kk = 0; kk < 2; kk++) {
      int ko = kk * 32 + (lane >> 4) * 8;
      int kosw = ko ^ ((lane & 7) << 3);       // T2 read: r&7 == lane&7
      bf16x8 af[4], bfr[4];
#pragma unroll
      for (int mi = 0; mi < 4; mi++)
        af[mi] = *(const bf16x8*)&As[(wr * 64 + mi * 16 + (lane & 15)) * 64 + kosw];
#pragma unroll
      for (int ni = 0; ni < 4; ni++)
        bfr[ni] = *(const bf16x8*)&Bs[(wc * 64 + ni * 16 + (lane & 15)) * 64 + kosw];
#pragma unroll
      for (int mi = 0; mi < 4; mi++)
#pragma unroll
        for (int ni = 0; ni < 4; ni++)
          acc[mi][ni] = __builtin_amdgcn_mfma_f32_16x16x32_bf16(
              af[mi], bfr[ni], acc[mi][ni], 0, 0, 0);
    }
  }

  // epilogue: +bias, split columns into C0/C1, guard rows
  int ncol_tile = tn * 128;
  OutT* Cd; const float* bs; int col0;
  if (ncol_tile < nsplit) { Cd = C0; bs = bias0; col0 = ncol_tile; }
  else { Cd = C1; bs = bias1; col0 = ncol_tile - nsplit; }
#pragma unroll
  for (int mi = 0; mi < 4; mi++) {
    int rbase = tm * 128 + wr * 64 + mi * 16 + (lane >> 4) * 4;
#pragma unroll
    for (int ni = 0; ni < 4; ni++) {
      int c = col0 + wc * 64 + ni * 16 + (lane & 15);
      float bv = bs[c];
#pragma unroll
      for (int j = 0; j < 4; j++) {
        int r = rbase + j;
        if (r < M) {
          float v = acc[mi][ni][j] + bv;
          if constexpr (sizeof(OutT) == 2) Cd[(size_t)r * nsplit + c] = f2bf(v);
          else Cd[(size_t)r * nsplit + c] = v;
        }
      }
    }
  }
}

// ---------------- CSR build ----------------
__global__ void deg_init_kernel(int* deg, float* stats, int n) {
  int i = blockIdx.x * 256 + threadIdx.x;
  if (i < n) deg[i] = 1;  // self loop
  if (i < 1024) stats[i] = 0.f;
}
__global__ void hist_kernel(const int* __restrict__ dst, int* deg, int E) {
  int e = blockIdx.x * 256 + threadIdx.x;
  if (e < E) atomicAdd(&deg[dst[e]], 1);
}
// parallel scan: (1) per-block scan + totals, (2) 1-wave scan of totals,
// (3) add block bases -> off & cursor
__global__ __launch_bounds__(1024) void scan1_kernel(
    const int* __restrict__ deg, int* __restrict__ off, int* __restrict__ btot, int n) {
  __shared__ int wsum[16];
  int tid = threadIdx.x, lane = tid & 63, w = tid >> 6;
  int i = blockIdx.x * 1024 + tid;
  int v = (i < n) ? deg[i] : 0;
  int s = v;
#pragma unroll
  for (int d = 1; d < 64; d <<= 1) {
    int t = __shfl_up(s, d);
    if (lane >= d) s += t;
  }
  if (lane == 63) wsum[w] = s;
  __syncthreads();
  if (w == 0 && lane < 16) {
    int t = wsum[lane];
#pragma unroll
    for (int d = 1; d < 16; d <<= 1) {
      int u = __shfl_up(t, d);
      if (lane >= d) t += u;
    }
    wsum[lane] = t;
  }
  __syncthreads();
  int incl = (w ? wsum[w - 1] : 0) + s;
  if (i < n) off[i] = incl - v;               // block-local exclusive
  if (tid == 1023) btot[blockIdx.x] = incl;
}
__global__ void scan2_kernel(const int* __restrict__ btot, int* __restrict__ gbase,
                             int* __restrict__ off, int nb, int n) {
  int lane = threadIdx.x;
  int v = lane < nb ? btot[lane] : 0;
  int s = v;
#pragma unroll
  for (int d = 1; d < 64; d <<= 1) {
    int t = __shfl_up(s, d);
    if (lane >= d) s += t;
  }
  if (lane < nb) gbase[lane] = s - v;
  if (lane == nb - 1) off[n] = s;             // grand total
}
__global__ __launch_bounds__(1024) void scan3_kernel(
    int* __restrict__ off, int* __restrict__ cursor,
    const int* __restrict__ gbase, int n) {
  int i = blockIdx.x * 1024 + threadIdx.x;
  if (i < n) {
    int v = off[i] + gbase[blockIdx.x];
    off[i] = v;
    cursor[i] = v;
  }
}
__global__ void scatter_kernel(const int* __restrict__ src, const int* __restrict__ dst,
                               int* cursor, int* __restrict__ esrc, int E, int n) {
  int e = blockIdx.x * 256 + threadIdx.x;
  if (e < E) {
    int d = dst[e];
    int pos = atomicAdd(&cursor[d], 1);
    esrc[pos] = src[e];
  } else if (e < E + n) {
    int i = e - E;
    int pos = atomicAdd(&cursor[i], 1);
    esrc[pos] = i;
  }
}

// ---------------- GATv2 aggregate: one wave per node, online softmax ----------
// bf16 features, one-edge-deep raw prefetch to hide the gather latency.
template <int VPL>
__global__ __launch_bounds__(256) void gat_agg_kernel(
    const unsigned short* __restrict__ xl, const unsigned short* __restrict__ xr,
    const float* __restrict__ att, const float* __restrict__ bias,
    const int* __restrict__ off, const int* __restrict__ esrc,
    float* __restrict__ out, int n, int do_relu) {
  constexpr int C = VPL * 64;
  using RawT = std::conditional_t<VPL == 8, bf16x8, unsigned int>;
  int node = blockIdx.x * 4 + (threadIdx.x >> 6);
  if (node >= n) return;
  int lane = threadIdx.x & 63;
  int base = lane * VPL;
  float xrv[VPL], attv[VPL], acc[VPL];
#pragma unroll
  for (int v = 0; v < VPL; v++) {
    xrv[v] = bf2f(xr[(size_t)node * C + base + v]);
    attv[v] = att[base + v];
    acc[v] = 0.f;
  }
  float m = -1e30f, s = 0.f;
  int e0 = off[node], e1 = off[node + 1];   // e1 > e0 guaranteed (self loop)
  RawT nxt = *(const RawT*)(xl + (size_t)esrc[e0] * C + base);
  for (int e = e0; e < e1; e++) {
    RawT cur = nxt;
    int en = (e + 1 < e1) ? e + 1 : e;      // harmless reload on last iter
    nxt = *(const RawT*)(xl + (size_t)esrc[en] * C + base);
    float xlv[VPL];
    if constexpr (VPL == 8) {
#pragma unroll
      for (int v = 0; v < 8; v++) xlv[v] = bf2f((unsigned short)cur[v]);
    } else {
      xlv[0] = bf2f((unsigned short)(cur & 0xffffu));
      xlv[1] = bf2f((unsigned short)(cur >> 16));
    }
    float p = 0.f;
#pragma unroll
    for (int v = 0; v < VPL; v++) {
      float t = xlv[v] + xrv[v];
      t = t > 0.f ? t : 0.2f * t;   // leaky_relu(0.2)
      p += attv[v] * t;
    }
#pragma unroll
    for (int d2 = 32; d2; d2 >>= 1) p += __shfl_xor(p, d2);
    float mn = fmaxf(m, p);
    float scale = __expf(m - mn);
    float w = __expf(p - mn);
    s = s * scale + w;
#pragma unroll
    for (int v = 0; v < VPL; v++) acc[v] = acc[v] * scale + w * xlv[v];
    m = mn;
  }
  float inv = 1.f / (s + 1e-16f);
#pragma unroll
  for (int v = 0; v < VPL; v++) {
    float o = acc[v] * inv + bias[base + v];
    if (do_relu) o = fmaxf(o, 0.f);
    out[(size_t)node * C + base + v] = o;
  }
}

// ---------------- BatchNorm (training stats) ----------------
__global__ __launch_bounds__(256) void bn_stats_kernel(
    const float* __restrict__ h1, float* __restrict__ stats, int n) {
  int tid = threadIdx.x;
  int r0 = blockIdx.x * 128;
  int r1 = r0 + 128 < n ? r0 + 128 : n;
  float s0 = 0, s1 = 0, q0 = 0, q1 = 0;
  for (int r = r0; r < r1; ++r) {
    float a = h1[(size_t)r * 512 + tid];
    float b = h1[(size_t)r * 512 + tid + 256];
    s0 += a; q0 += a * a; s1 += b; q1 += b * b;
  }
  atomicAdd(&stats[tid], s0);
  atomicAdd(&stats[tid + 256], s1);
  atomicAdd(&stats[512 + tid], q0);
  atomicAdd(&stats[512 + tid + 256], q1);
}
__global__ __launch_bounds__(256) void bn_norm_kernel(
    const float* __restrict__ h1, const float* __restrict__ stats,
    const float* __restrict__ gamma, const float* __restrict__ beta,
    unsigned short* __restrict__ hbn, int n) {
  int idx = blockIdx.x * 256 + threadIdx.x;  // over MPAD*512/4
  int i0 = idx * 4;
  int r = i0 >> 9, c = i0 & 511;
  if (r >= n) {
    ushort4 z = {0, 0, 0, 0};
    *(ushort4*)&hbn[i0] = z;
    return;
  }
  float4 hv = *(const float4*)&h1[i0];
  ushort4 o;
  float vv[4] = {hv.x, hv.y, hv.z, hv.w};
  unsigned short* op = (unsigned short*)&o;
#pragma unroll
  for (int j = 0; j < 4; j++) {
    float mean = stats[c + j] * (1.f / NN);
    float var = stats[512 + c + j] * (1.f / NN) - mean * mean;
    float invs = rsqrtf(var + 1e-5f);
    op[j] = f2bf(gamma[c + j] * (vv[j] - mean) * invs + beta[c + j]);
  }
  *(ushort4*)&hbn[i0] = o;
}

// ---------------- launch ----------------
extern "C" void kernel_launch(void* const* d_in, const int* in_sizes, int n_in,
                              void* d_out, int out_size, void* d_ws, size_t ws_size,
                              hipStream_t stream) {
  (void)in_sizes; (void)n_in; (void)out_size; (void)ws_size;
  const float* x      = (const float*)d_in[0];
  const int*   ei     = (const int*)d_in[1];
  const float* conv_w = (const float*)d_in[2];
  const float* conv_b = (const float*)d_in[3];
  const float* W1l    = (const float*)d_in[4];
  const float* b1l    = (const float*)d_in[5];
  const float* W1r    = (const float*)d_in[6];
  const float* b1r    = (const float*)d_in[7];
  const float* att1   = (const float*)d_in[8];
  const float* bias1  = (const float*)d_in[9];
  const float* gamma  = (const float*)d_in[10];
  const float* beta   = (const float*)d_in[11];
  const float* W2l    = (const float*)d_in[12];
  const float* b2l    = (const float*)d_in[13];
  const float* W2r    = (const float*)d_in[14];
  const float* b2r    = (const float*)d_in[15];
  const float* att2   = (const float*)d_in[16];
  const float* bias2  = (const float*)d_in[17];

  char* ws = (char*)d_ws;
  size_t off = 0;
  auto alloc = [&](size_t bytes) {
    size_t r = off;
    off += (bytes + 255) & ~(size_t)255;
    return r;
  };
  size_t o_h    = alloc((size_t)MPAD * 2048 * 2);  // bf16 h; reused for stage-2 bufs
  size_t o_wc1  = alloc((size_t)1024 * 2048 * 2);
  size_t o_wc2  = alloc((size_t)256 * 512 * 2);
  size_t o_xl1  = alloc((size_t)NN * 512 * 2);     // bf16
  size_t o_xr1  = alloc((size_t)NN * 512 * 2);
  size_t o_off  = alloc((size_t)(NN + 1) * 4);
  size_t o_cur  = alloc((size_t)NN * 4);
  size_t o_deg  = alloc((size_t)NN * 4);
  size_t o_esrc = alloc((size_t)ETOT * 4);
  size_t o_stats = alloc((size_t)1024 * 4);
  size_t o_btot  = alloc((size_t)64 * 4);
  size_t o_gbase = alloc((size_t)64 * 4);

  unsigned short* h   = (unsigned short*)(ws + o_h);
  unsigned short* wc1 = (unsigned short*)(ws + o_wc1);
  unsigned short* wc2 = (unsigned short*)(ws + o_wc2);
  unsigned short* xl1 = (unsigned short*)(ws + o_xl1);
  unsigned short* xr1 = (unsigned short*)(ws + o_xr1);
  int* offp  = (int*)(ws + o_off);
  int* curp  = (int*)(ws + o_cur);
  int* degp  = (int*)(ws + o_deg);
  int* esrc  = (int*)(ws + o_esrc);
  float* stats = (float*)(ws + o_stats);
  int* btot  = (int*)(ws + o_btot);
  int* gbase = (int*)(ws + o_gbase);
  // stage-2 buffers aliased into the (dead-after-GEMM1) h region:
  float* h1 = (float*)(ws + o_h);                               // 40,960,000 B
  unsigned short* hbn = (unsigned short*)(ws + o_h + 40960000); // 20,578,304 B
  unsigned short* xl2 = (unsigned short*)(ws + o_h + 40960000 + 20578304); // 5,120,000 B
  unsigned short* xr2 = (unsigned short*)(ws + o_h + 40960000 + 20578304 + 5120000);

  const int* src_raw = ei;
  const int* dst_raw = ei + ERAW;
  float* mu = (float*)d_out;

  conv_kernel<<<MPAD, 256, 0, stream>>>(x, conv_w, conv_b, h);
  wprep_kernel<<<dim3(2048 / 32, 1024 / 32), 256, 0, stream>>>(W1l, W1r, wc1, 2048, 512);
  wprep_kernel<<<dim3(512 / 32, 256 / 32), 256, 0, stream>>>(W2l, W2r, wc2, 512, 128);

  deg_init_kernel<<<(NN + 255) / 256, 256, 0, stream>>>(degp, stats, NN);
  hist_kernel<<<(ERAW + 255) / 256, 256, 0, stream>>>(dst_raw, degp, ERAW);
  const int NB = (NN + 1023) / 1024;  // 20
  scan1_kernel<<<NB, 1024, 0, stream>>>(degp, offp, btot, NN);
  scan2_kernel<<<1, 64, 0, stream>>>(btot, gbase, offp, NB, NN);
  scan3_kernel<<<NB, 1024, 0, stream>>>(offp, curp, gbase, NN);
  scatter_kernel<<<(ETOT + 255) / 256, 256, 0, stream>>>(src_raw, dst_raw, curp, esrc, ERAW, NN);

  // layer 1 (bf16 xl/xr for the gather)
  gemm_kernel<unsigned short><<<(MPAD / 128) * (1024 / 128), 256, 0, stream>>>(
      h, wc1, b1l, b1r, xl1, xr1, NN, 2048, 8, 512, 1);
  gat_agg_kernel<8><<<NN / 4, 256, 0, stream>>>(
      xl1, xr1, att1, bias1, offp, esrc, h1, NN, 1);

  // batchnorm
  bn_stats_kernel<<<(NN + 127) / 128, 256, 0, stream>>>(h1, stats, NN);
  bn_norm_kernel<<<(MPAD * 512 / 4) / 256, 256, 0, stream>>>(h1, stats, gamma, beta, hbn, NN);

  // layer 2 (bf16 xl/xr too; fp32 accumulate in agg -> mu)
  gemm_kernel<unsigned short><<<(MPAD / 128) * (256 / 128), 256, 0, stream>>>(
      hbn, wc2, b2l, b2r, xl2, xr2, NN, 512, 2, 128, 0);
  gat_agg_kernel<2><<<NN / 4, 256, 0, stream>>>(
      xl2, xr2, att2, bias2, offp, esrc, mu, NN, 0);
}

// Round 4
// 349.199 us; speedup vs baseline: 1.6278x; 1.0985x over previous
//
#include <hip/hip_runtime.h>
#include <cstdint>
#include <cstddef>
#include <type_traits>

static constexpr int NN   = 20000;     // nodes
static constexpr int MPAD = 20096;     // 157 * 128
static constexpr int ERAW = 320000;    // given edges
static constexpr int ETOT = ERAW + NN; // + self loops

typedef __attribute__((ext_vector_type(8))) short bf16x8;
typedef __attribute__((ext_vector_type(8))) unsigned short u16x8;
typedef __attribute__((ext_vector_type(4))) float f32x4;

__device__ __forceinline__ unsigned short f2bf(float f) {
  union { float f; unsigned u; } v; v.f = f;
  unsigned r = v.u + 0x7fffu + ((v.u >> 16) & 1u);
  return (unsigned short)(r >> 16);
}
__device__ __forceinline__ float bf2f(unsigned short u) {
  union { unsigned u; float f; } v; v.u = ((unsigned)u) << 16;
  return v.f;
}

__device__ __forceinline__ void gload_lds16(const void* g, void* l) {
  __builtin_amdgcn_global_load_lds(
      (const __attribute__((address_space(1))) unsigned int*)g,
      (__attribute__((address_space(3))) unsigned int*)l, 16, 0, 0);
}

// ---------------- x fp32 -> bf16 cast (pad rows zero) -------------------------
__global__ __launch_bounds__(256) void cast_x_kernel(
    const float* __restrict__ x, unsigned short* __restrict__ xb) {
  int i8 = blockIdx.x * 256 + threadIdx.x;   // 8-elem chunk; 96 chunks/row
  size_t base = (size_t)i8 * 8;
  int row = i8 / 96;
  u16x8 o;
  if (row < NN) {
    float4 a = *(const float4*)&x[base];
    float4 b = *(const float4*)&x[base + 4];
    o[0] = f2bf(a.x); o[1] = f2bf(a.y); o[2] = f2bf(a.z); o[3] = f2bf(a.w);
    o[4] = f2bf(b.x); o[5] = f2bf(b.y); o[6] = f2bf(b.z); o[7] = f2bf(b.w);
  } else {
#pragma unroll
    for (int j = 0; j < 8; j++) o[j] = 0;
  }
  *(u16x8*)&xb[base] = o;
}

// ---------------- conv folded into W1: Weff^T[c][k*32+t], beff1[c] ------------
// Weff[(k,t),c] = sum_o conv_w[o,k] * W1[o*32+t, c]
// beff1[c] = b1[c] + sum_{o,t} conv_b[o] * W1[o*32+t, c]   (atomicAdd over t-blocks)
__global__ __launch_bounds__(256) void weff_kernel(
    const float* __restrict__ conv_w, const float* __restrict__ conv_b,
    const float* __restrict__ W1l, const float* __restrict__ b1l,
    const float* __restrict__ W1r, const float* __restrict__ b1r,
    unsigned short* __restrict__ wc1, float* __restrict__ beff1) {
  __shared__ float ws[64 * 24];
  int t = blockIdx.x;                 // 0..31
  int tid = threadIdx.x;
  for (int i = tid; i < 64 * 24; i += 256) ws[i] = conv_w[i];
  __syncthreads();
  int c = blockIdx.y * 256 + tid;     // 0..1023
  const float* W; const float* bb; int cl;
  if (c < 512) { W = W1l; bb = b1l; cl = c; } else { W = W1r; bb = b1r; cl = c - 512; }
  float acc[24];
#pragma unroll
  for (int k = 0; k < 24; k++) acc[k] = 0.f;
  float bacc = (t == 0) ? bb[cl] : 0.f;
  for (int o = 0; o < 64; o++) {
    float Wv = W[(size_t)(o * 32 + t) * 512 + cl];
    bacc += conv_b[o] * Wv;
#pragma unroll
    for (int k = 0; k < 24; k++) acc[k] += ws[o * 24 + k] * Wv;
  }
#pragma unroll
  for (int k = 0; k < 24; k++) wc1[(size_t)c * 768 + k * 32 + t] = f2bf(acc[k]);
  atomicAdd(&beff1[c], bacc);
}

// ---------------- BN folded into W2 (runs after bn_stats) ---------------------
__global__ __launch_bounds__(256) void w2eff_kernel(
    const float* __restrict__ stats, const float* __restrict__ gamma,
    const float* __restrict__ beta,
    const float* __restrict__ W2l, const float* __restrict__ b2l,
    const float* __restrict__ W2r, const float* __restrict__ b2r,
    unsigned short* __restrict__ wc2, float* __restrict__ beff2) {
  int c = threadIdx.x;                // 0..255
  const float* W; const float* bb; int cl;
  if (c < 128) { W = W2l; bb = b2l; cl = c; } else { W = W2r; bb = b2r; cl = c - 128; }
  float bacc = bb[cl];
  for (int k = 0; k < 512; k++) {
    float mean = stats[k] * (1.f / NN);
    float var = stats[512 + k] * (1.f / NN) - mean * mean;
    float rstd = rsqrtf(var + 1e-5f);
    float sc = gamma[k] * rstd;
    float sh = beta[k] - sc * mean;
    float wv = W[(size_t)k * 128 + cl];
    wc2[(size_t)c * 512 + k] = f2bf(sc * wv);
    bacc += sh * wv;
  }
  beff2[c] = bacc;
}

// ---------------- bf16 MFMA GEMM (m97 2-phase + T2 swizzle + T1) --------------
// C[M][2*nsplit] = A[MPAD][K] * B^T[N][K] + bias; 128x128 tile, BK=64, 4 waves.
template <typename OutT>
__global__ __launch_bounds__(256, 5) void gemm_kernel(
    const unsigned short* __restrict__ A, const unsigned short* __restrict__ B,
    const float* __restrict__ bias0, const float* __restrict__ bias1,
    OutT* __restrict__ C0, OutT* __restrict__ C1,
    int M, int K, int NT, int nsplit, int swz) {
  __shared__ __align__(16) unsigned short As[128 * 64];
  __shared__ __align__(16) unsigned short Bs[128 * 64];
  int bid = blockIdx.x;
  if (swz) bid = (bid & 7) * (gridDim.x >> 3) + (bid >> 3);  // XCD-chunked (nwg%8==0)
  int tm = bid / NT, tn = bid % NT;
  int tid = threadIdx.x, wid = tid >> 6, lane = tid & 63;
  int wr = wid >> 1, wc = wid & 1;
  const unsigned short* gA = A + (size_t)(tm * 128) * K;
  const unsigned short* gB = B + (size_t)(tn * 128) * K;
  int srow = wid * 8 + (lane >> 3);
  int scol = ((lane & 7) ^ (lane >> 3)) * 8;   // T2: srow&7 == lane>>3

  f32x4 acc[4][4];
  f32x4 zero = {0.f, 0.f, 0.f, 0.f};
#pragma unroll
  for (int i = 0; i < 4; i++)
#pragma unroll
    for (int j = 0; j < 4; j++) acc[i][j] = zero;

  int KT = K >> 6;
  for (int kt = 0; kt < KT; ++kt) {
    if (kt) __syncthreads();
    {
      const unsigned short* a0 = gA + (size_t)srow * K + kt * 64 + scol;
      const unsigned short* b0 = gB + (size_t)srow * K + kt * 64 + scol;
#pragma unroll
      for (int i = 0; i < 4; i++)
        gload_lds16(a0 + (size_t)i * 32 * K, &As[i * 2048 + wid * 512]);
#pragma unroll
      for (int i = 0; i < 4; i++)
        gload_lds16(b0 + (size_t)i * 32 * K, &Bs[i * 2048 + wid * 512]);
    }
    asm volatile("s_waitcnt vmcnt(0)" ::: "memory");
    __syncthreads();
#pragma unroll
    for (int kk = 0; kk < 2; kk++) {
      int ko = kk * 32 + (lane >> 4) * 8;
      int kosw = ko ^ ((lane & 7) << 3);       // T2 read: r&7 == lane&7
      bf16x8 af[4], bfr[4];
#pragma unroll
      for (int mi = 0; mi < 4; mi++)
        af[mi] = *(const bf16x8*)&As[(wr * 64 + mi * 16 + (lane & 15)) * 64 + kosw];
#pragma unroll
      for (int ni = 0; ni < 4; ni++)
        bfr[ni] = *(const bf16x8*)&Bs[(wc * 64 + ni * 16 + (lane & 15)) * 64 + kosw];
#pragma unroll
      for (int mi = 0; mi < 4; mi++)
#pragma unroll
        for (int ni = 0; ni < 4; ni++)
          acc[mi][ni] = __builtin_amdgcn_mfma_f32_16x16x32_bf16(
              af[mi], bfr[ni], acc[mi][ni], 0, 0, 0);
    }
  }

  int ncol_tile = tn * 128;
  OutT* Cd; const float* bs; int col0;
  if (ncol_tile < nsplit) { Cd = C0; bs = bias0; col0 = ncol_tile; }
  else { Cd = C1; bs = bias1; col0 = ncol_tile - nsplit; }
#pragma unroll
  for (int mi = 0; mi < 4; mi++) {
    int rbase = tm * 128 + wr * 64 + mi * 16 + (lane >> 4) * 4;
#pragma unroll
    for (int ni = 0; ni < 4; ni++) {
      int c = col0 + wc * 64 + ni * 16 + (lane & 15);
      float bv = bs[c];
#pragma unroll
      for (int j = 0; j < 4; j++) {
        int r = rbase + j;
        if (r < M) {
          float v = acc[mi][ni][j] + bv;
          if constexpr (sizeof(OutT) == 2) Cd[(size_t)r * nsplit + c] = f2bf(v);
          else Cd[(size_t)r * nsplit + c] = v;
        }
      }
    }
  }
}

// ---------------- CSR build (self-loop placed first per segment) --------------
__global__ void hist_kernel(const int* __restrict__ dst, int* deg, int E) {
  int e = blockIdx.x * 256 + threadIdx.x;
  if (e < E) atomicAdd(&deg[dst[e]], 1);
}
__global__ __launch_bounds__(1024) void scan1_kernel(
    const int* __restrict__ deg, int* __restrict__ off, int* __restrict__ btot, int n) {
  __shared__ int wsum[16];
  int tid = threadIdx.x, lane = tid & 63, w = tid >> 6;
  int i = blockIdx.x * 1024 + tid;
  int v = (i < n) ? deg[i] + 1 : 0;    // +1 self loop
  int s = v;
#pragma unroll
  for (int d = 1; d < 64; d <<= 1) {
    int t = __shfl_up(s, d);
    if (lane >= d) s += t;
  }
  if (lane == 63) wsum[w] = s;
  __syncthreads();
  if (w == 0 && lane < 16) {
    int t = wsum[lane];
#pragma unroll
    for (int d = 1; d < 16; d <<= 1) {
      int u = __shfl_up(t, d);
      if (lane >= d) t += u;
    }
    wsum[lane] = t;
  }
  __syncthreads();
  int incl = (w ? wsum[w - 1] : 0) + s;
  if (i < n) off[i] = incl - v;               // block-local exclusive
  if (tid == 1023) btot[blockIdx.x] = incl;
}
__global__ void scan2_kernel(const int* __restrict__ btot, int* __restrict__ gbase,
                             int* __restrict__ off, int nb, int n) {
  int lane = threadIdx.x;
  int v = lane < nb ? btot[lane] : 0;
  int s = v;
#pragma unroll
  for (int d = 1; d < 64; d <<= 1) {
    int t = __shfl_up(s, d);
    if (lane >= d) s += t;
  }
  if (lane < nb) gbase[lane] = s - v;
  if (lane == nb - 1) off[n] = s;
}
__global__ __launch_bounds__(1024) void scan3_kernel(
    int* __restrict__ off, int* __restrict__ cursor,
    const int* __restrict__ gbase, int* __restrict__ esrc, int n) {
  int i = blockIdx.x * 1024 + threadIdx.x;
  if (i < n) {
    int v = off[i] + gbase[blockIdx.x];
    off[i] = v;
    cursor[i] = v + 1;    // slot v reserved for self loop
    esrc[v] = i;
  }
}
__global__ void scatter_kernel(const int* __restrict__ src, const int* __restrict__ dst,
                               int* cursor, int* __restrict__ esrc, int E) {
  int e = blockIdx.x * 256 + threadIdx.x;
  if (e < E) {
    int pos = atomicAdd(&cursor[dst[e]], 1);
    esrc[pos] = src[e];
  }
}

// ---------------- GATv2 aggregate: one wave/node, no-max softmax, ILP-2 -------
template <int VPL, typename OutT>
__global__ __launch_bounds__(256) void gat_agg_kernel(
    const unsigned short* __restrict__ xl, const unsigned short* __restrict__ xr,
    const float* __restrict__ att, const float* __restrict__ bias,
    const int* __restrict__ off, const int* __restrict__ esrc,
    OutT* __restrict__ out, int n, int do_relu) {
  constexpr int C = VPL * 64;
  using RawT = std::conditional_t<VPL == 8, bf16x8, unsigned int>;
  int node = blockIdx.x * 4 + (threadIdx.x >> 6);
  if (node >= n) return;
  int lane = threadIdx.x & 63;
  int base = lane * VPL;
  float xrv[VPL], attv[VPL];
#pragma unroll
  for (int v = 0; v < VPL; v++) {
    xrv[v] = bf2f(xr[(size_t)node * C + base + v]);
    attv[v] = att[base + v];
  }
  float s0 = 0.f, s1 = 0.f;
  float acc0[VPL], acc1[VPL];
#pragma unroll
  for (int v = 0; v < VPL; v++) { acc0[v] = 0.f; acc1[v] = 0.f; }
  int e0 = off[node], e1 = off[node + 1];
  int e = e0;
  for (; e + 1 < e1; e += 2) {
    RawT r0 = *(const RawT*)(xl + (size_t)esrc[e] * C + base);
    RawT r1 = *(const RawT*)(xl + (size_t)esrc[e + 1] * C + base);
    float x0[VPL], x1[VPL];
    if constexpr (VPL == 8) {
#pragma unroll
      for (int v = 0; v < 8; v++) { x0[v] = bf2f((unsigned short)r0[v]);
                                    x1[v] = bf2f((unsigned short)r1[v]); }
    } else {
      x0[0] = bf2f((unsigned short)(r0 & 0xffffu)); x0[1] = bf2f((unsigned short)(r0 >> 16));
      x1[0] = bf2f((unsigned short)(r1 & 0xffffu)); x1[1] = bf2f((unsigned short)(r1 >> 16));
    }
    float p0 = 0.f, p1 = 0.f;
#pragma unroll
    for (int v = 0; v < VPL; v++) {
      float t0 = x0[v] + xrv[v]; t0 = t0 > 0.f ? t0 : 0.2f * t0;
      float t1 = x1[v] + xrv[v]; t1 = t1 > 0.f ? t1 : 0.2f * t1;
      p0 += attv[v] * t0;
      p1 += attv[v] * t1;
    }
#pragma unroll
    for (int d2 = 32; d2; d2 >>= 1) { p0 += __shfl_xor(p0, d2); p1 += __shfl_xor(p1, d2); }
    float w0 = __expf(p0), w1 = __expf(p1);
    s0 += w0; s1 += w1;
#pragma unroll
    for (int v = 0; v < VPL; v++) { acc0[v] += w0 * x0[v]; acc1[v] += w1 * x1[v]; }
  }
  if (e < e1) {
    RawT r0 = *(const RawT*)(xl + (size_t)esrc[e] * C + base);
    float x0[VPL];
    if constexpr (VPL == 8) {
#pragma unroll
      for (int v = 0; v < 8; v++) x0[v] = bf2f((unsigned short)r0[v]);
    } else {
      x0[0] = bf2f((unsigned short)(r0 & 0xffffu)); x0[1] = bf2f((unsigned short)(r0 >> 16));
    }
    float p0 = 0.f;
#pragma unroll
    for (int v = 0; v < VPL; v++) {
      float t0 = x0[v] + xrv[v]; t0 = t0 > 0.f ? t0 : 0.2f * t0;
      p0 += attv[v] * t0;
    }
#pragma unroll
    for (int d2 = 32; d2; d2 >>= 1) p0 += __shfl_xor(p0, d2);
    float w0 = __expf(p0);
    s0 += w0;
#pragma unroll
    for (int v = 0; v < VPL; v++) acc0[v] += w0 * x0[v];
  }
  float inv = 1.f / (s0 + s1 + 1e-16f);
#pragma unroll
  for (int v = 0; v < VPL; v++) {
    float o = (acc0[v] + acc1[v]) * inv + bias[base + v];
    if (do_relu) o = fmaxf(o, 0.f);
    if constexpr (sizeof(OutT) == 2) out[(size_t)node * C + base + v] = f2bf(o);
    else out[(size_t)node * C + base + v] = o;
  }
}

// ---------------- BN stats from bf16 h1 ---------------------------------------
__global__ __launch_bounds__(256) void bn_stats_kernel(
    const unsigned short* __restrict__ h1, float* __restrict__ stats, int n) {
  int tid = threadIdx.x;
  int c0 = tid * 2;
  int r0 = blockIdx.x * 128;
  int r1 = r0 + 128 < n ? r0 + 128 : n;
  float s0 = 0, q0 = 0, s1 = 0, q1 = 0;
  for (int r = r0; r < r1; ++r) {
    unsigned u = *(const unsigned*)&h1[(size_t)r * 512 + c0];
    float a = bf2f((unsigned short)(u & 0xffffu));
    float b = bf2f((unsigned short)(u >> 16));
    s0 += a; q0 += a * a; s1 += b; q1 += b * b;
  }
  atomicAdd(&stats[c0], s0);
  atomicAdd(&stats[c0 + 1], s1);
  atomicAdd(&stats[512 + c0], q0);
  atomicAdd(&stats[512 + c0 + 1], q1);
}

// ---------------- launch ----------------
extern "C" void kernel_launch(void* const* d_in, const int* in_sizes, int n_in,
                              void* d_out, int out_size, void* d_ws, size_t ws_size,
                              hipStream_t stream) {
  (void)in_sizes; (void)n_in; (void)out_size; (void)ws_size;
  const float* x      = (const float*)d_in[0];
  const int*   ei     = (const int*)d_in[1];
  const float* conv_w = (const float*)d_in[2];
  const float* conv_b = (const float*)d_in[3];
  const float* W1l    = (const float*)d_in[4];
  const float* b1l    = (const float*)d_in[5];
  const float* W1r    = (const float*)d_in[6];
  const float* b1r    = (const float*)d_in[7];
  const float* att1   = (const float*)d_in[8];
  const float* bias1  = (const float*)d_in[9];
  const float* gamma  = (const float*)d_in[10];
  const float* beta   = (const float*)d_in[11];
  const float* W2l    = (const float*)d_in[12];
  const float* b2l    = (const float*)d_in[13];
  const float* W2r    = (const float*)d_in[14];
  const float* b2r    = (const float*)d_in[15];
  const float* att2   = (const float*)d_in[16];
  const float* bias2  = (const float*)d_in[17];

  char* ws = (char*)d_ws;
  size_t off = 0;
  auto alloc = [&](size_t bytes) {
    size_t r = off;
    off += (bytes + 255) & ~(size_t)255;
    return r;
  };
  size_t o_xb   = alloc((size_t)MPAD * 768 * 2);   // bf16 x (A of GEMM1)
  size_t o_wc1  = alloc((size_t)1024 * 768 * 2);   // Weff^T bf16
  size_t o_wc2  = alloc((size_t)256 * 512 * 2);    // W2eff^T bf16
  size_t o_xl1  = alloc((size_t)NN * 512 * 2);
  size_t o_xr1  = alloc((size_t)NN * 512 * 2);
  size_t o_h1   = alloc((size_t)MPAD * 512 * 2);   // bf16 relu(agg1)
  size_t o_xl2  = alloc((size_t)NN * 128 * 2);
  size_t o_xr2  = alloc((size_t)NN * 128 * 2);
  size_t o_off  = alloc((size_t)(NN + 1) * 4);
  size_t o_cur  = alloc((size_t)NN * 4);
  size_t o_deg  = alloc((size_t)NN * 4);
  size_t o_esrc = alloc((size_t)ETOT * 4);
  size_t o_stats = alloc((size_t)1024 * 4);
  size_t o_beff1 = alloc((size_t)1024 * 4);
  size_t o_beff2 = alloc((size_t)256 * 4);
  size_t o_btot  = alloc((size_t)64 * 4);
  size_t o_gbase = alloc((size_t)64 * 4);

  unsigned short* xb  = (unsigned short*)(ws + o_xb);
  unsigned short* wc1 = (unsigned short*)(ws + o_wc1);
  unsigned short* wc2 = (unsigned short*)(ws + o_wc2);
  unsigned short* xl1 = (unsigned short*)(ws + o_xl1);
  unsigned short* xr1 = (unsigned short*)(ws + o_xr1);
  unsigned short* h1  = (unsigned short*)(ws + o_h1);
  unsigned short* xl2 = (unsigned short*)(ws + o_xl2);
  unsigned short* xr2 = (unsigned short*)(ws + o_xr2);
  int* offp  = (int*)(ws + o_off);
  int* curp  = (int*)(ws + o_cur);
  int* degp  = (int*)(ws + o_deg);
  int* esrc  = (int*)(ws + o_esrc);
  float* stats = (float*)(ws + o_stats);
  float* beff1 = (float*)(ws + o_beff1);
  float* beff2 = (float*)(ws + o_beff2);
  int* btot  = (int*)(ws + o_btot);
  int* gbase = (int*)(ws + o_gbase);

  const int* src_raw = ei;
  const int* dst_raw = ei + ERAW;
  float* mu = (float*)d_out;

  hipMemsetAsync(stats, 0, 1024 * 4, stream);
  hipMemsetAsync(degp, 0, (size_t)NN * 4, stream);
  hipMemsetAsync(beff1, 0, 1024 * 4, stream);
  hipMemsetAsync(h1 + (size_t)NN * 512, 0, (size_t)(MPAD - NN) * 512 * 2, stream);

  cast_x_kernel<<<(MPAD * 96) / 256, 256, 0, stream>>>(x, xb);
  weff_kernel<<<dim3(32, 4), 256, 0, stream>>>(conv_w, conv_b, W1l, b1l, W1r, b1r, wc1, beff1);

  hist_kernel<<<(ERAW + 255) / 256, 256, 0, stream>>>(dst_raw, degp, ERAW);
  const int NB = (NN + 1023) / 1024;  // 20
  scan1_kernel<<<NB, 1024, 0, stream>>>(degp, offp, btot, NN);
  scan2_kernel<<<1, 64, 0, stream>>>(btot, gbase, offp, NB, NN);
  scan3_kernel<<<NB, 1024, 0, stream>>>(offp, curp, gbase, esrc, NN);
  scatter_kernel<<<(ERAW + 255) / 256, 256, 0, stream>>>(src_raw, dst_raw, curp, esrc, ERAW);

  // layer 1: xl1/xr1 = xb @ Weff + beff1   (conv folded in; K=768)
  gemm_kernel<unsigned short><<<(MPAD / 128) * (1024 / 128), 256, 0, stream>>>(
      xb, wc1, beff1, beff1 + 512, xl1, xr1, NN, 768, 8, 512, 1);
  gat_agg_kernel<8, unsigned short><<<NN / 4, 256, 0, stream>>>(
      xl1, xr1, att1, bias1, offp, esrc, h1, NN, 1);

  // batchnorm stats + fold into W2
  bn_stats_kernel<<<(NN + 127) / 128, 256, 0, stream>>>(h1, stats, NN);
  w2eff_kernel<<<1, 256, 0, stream>>>(stats, gamma, beta, W2l, b2l, W2r, b2r, wc2, beff2);

  // layer 2: xl2/xr2 = h1 @ W2eff + beff2  (BN folded in; K=512)
  gemm_kernel<unsigned short><<<(MPAD / 128) * (256 / 128), 256, 0, stream>>>(
      h1, wc2, beff2, beff2 + 128, xl2, xr2, NN, 512, 2, 128, 0);
  gat_agg_kernel<2, float><<<NN / 4, 256, 0, stream>>>(
      xl2, xr2, att2, bias2, offp, esrc, mu, NN, 0);
}

// Round 5
// 298.176 us; speedup vs baseline: 1.9064x; 1.1711x over previous
//
#include <hip/hip_runtime.h>
#include <cstdint>
#include <cstddef>
#include <type_traits>

static constexpr int NN   = 20000;     // nodes
static constexpr int MPAD = 20096;     // 157 * 128
static constexpr int ERAW = 320000;    // given edges
static constexpr int ETOT = ERAW + NN; // + self loops

typedef __attribute__((ext_vector_type(8))) short bf16x8;
typedef __attribute__((ext_vector_type(8))) unsigned short u16x8;
typedef __attribute__((ext_vector_type(4))) float f32x4;

__device__ __forceinline__ unsigned short f2bf(float f) {
  union { float f; unsigned u; } v; v.f = f;
  unsigned r = v.u + 0x7fffu + ((v.u >> 16) & 1u);
  return (unsigned short)(r >> 16);
}
__device__ __forceinline__ float bf2f(unsigned short u) {
  union { unsigned u; float f; } v; v.u = ((unsigned)u) << 16;
  return v.f;
}

__device__ __forceinline__ void gload_lds16(const void* g, void* l) {
  __builtin_amdgcn_global_load_lds(
      (const __attribute__((address_space(1))) unsigned int*)g,
      (__attribute__((address_space(3))) unsigned int*)l, 16, 0, 0);
}

// ---------------- zero init: degp[NN], stats[1024], beff1[1024] ---------------
__global__ __launch_bounds__(256) void zero_init_kernel(
    int* __restrict__ degp, float* __restrict__ stats, float* __restrict__ beff1, int n) {
  int i = blockIdx.x * 256 + threadIdx.x;
  if (i < n) degp[i] = 0;
  if (i < 1024) { stats[i] = 0.f; beff1[i] = 0.f; }
}

// ---------------- x fp32 -> bf16 cast (pad rows zero) -------------------------
__global__ __launch_bounds__(256) void cast_x_kernel(
    const float* __restrict__ x, unsigned short* __restrict__ xb) {
  int i8 = blockIdx.x * 256 + threadIdx.x;   // 8-elem chunk; 96 chunks/row
  size_t base = (size_t)i8 * 8;
  int row = i8 / 96;
  u16x8 o;
  if (row < NN) {
    float4 a = *(const float4*)&x[base];
    float4 b = *(const float4*)&x[base + 4];
    o[0] = f2bf(a.x); o[1] = f2bf(a.y); o[2] = f2bf(a.z); o[3] = f2bf(a.w);
    o[4] = f2bf(b.x); o[5] = f2bf(b.y); o[6] = f2bf(b.z); o[7] = f2bf(b.w);
  } else {
#pragma unroll
    for (int j = 0; j < 8; j++) o[j] = 0;
  }
  *(u16x8*)&xb[base] = o;
}

// ---------------- conv folded into W1: Weff^T[c][k*32+t], beff1[c] ------------
__global__ __launch_bounds__(256) void weff_kernel(
    const float* __restrict__ conv_w, const float* __restrict__ conv_b,
    const float* __restrict__ W1l, const float* __restrict__ b1l,
    const float* __restrict__ W1r, const float* __restrict__ b1r,
    unsigned short* __restrict__ wc1, float* __restrict__ beff1) {
  __shared__ float ws[64 * 24];
  int t = blockIdx.x;                 // 0..31
  int tid = threadIdx.x;
  for (int i = tid; i < 64 * 24; i += 256) ws[i] = conv_w[i];
  __syncthreads();
  int c = blockIdx.y * 256 + tid;     // 0..1023
  const float* W; const float* bb; int cl;
  if (c < 512) { W = W1l; bb = b1l; cl = c; } else { W = W1r; bb = b1r; cl = c - 512; }
  float acc[24];
#pragma unroll
  for (int k = 0; k < 24; k++) acc[k] = 0.f;
  float bacc = (t == 0) ? bb[cl] : 0.f;
  for (int o = 0; o < 64; o++) {
    float Wv = W[(size_t)(o * 32 + t) * 512 + cl];
    bacc += conv_b[o] * Wv;
#pragma unroll
    for (int k = 0; k < 24; k++) acc[k] += ws[o * 24 + k] * Wv;
  }
#pragma unroll
  for (int k = 0; k < 24; k++) wc1[(size_t)c * 768 + k * 32 + t] = f2bf(acc[k]);
  atomicAdd(&beff1[c], bacc);
}

// ---------------- BN scale/shift per channel ----------------------------------
__global__ __launch_bounds__(256) void bnscale_kernel(
    const float* __restrict__ stats, const float* __restrict__ gamma,
    const float* __restrict__ beta, float* __restrict__ scsh) {
  int k = blockIdx.x * 256 + threadIdx.x;   // 0..511
  float mean = stats[k] * (1.f / NN);
  float var = stats[512 + k] * (1.f / NN) - mean * mean;
  float rstd = rsqrtf(var + 1e-5f);
  float sc = gamma[k] * rstd;
  scsh[k] = sc;
  scsh[512 + k] = beta[k] - sc * mean;
}

// ---------------- BN folded into W2 (parallel: one block per output col) ------
__global__ __launch_bounds__(256) void w2fold_kernel(
    const float* __restrict__ scsh,
    const float* __restrict__ W2l, const float* __restrict__ b2l,
    const float* __restrict__ W2r, const float* __restrict__ b2r,
    unsigned short* __restrict__ wc2, float* __restrict__ beff2) {
  int c = blockIdx.x;                 // 0..255
  const float* W; const float* bb; int cl;
  if (c < 128) { W = W2l; bb = b2l; cl = c; } else { W = W2r; bb = b2r; cl = c - 128; }
  int tid = threadIdx.x, lane = tid & 63, wid = tid >> 6;
  float part = 0.f;
#pragma unroll
  for (int j = 0; j < 2; j++) {
    int k = tid * 2 + j;
    float wv = W[(size_t)k * 128 + cl];
    wc2[(size_t)c * 512 + k] = f2bf(scsh[k] * wv);
    part += scsh[512 + k] * wv;
  }
#pragma unroll
  for (int d = 32; d; d >>= 1) part += __shfl_xor(part, d);
  __shared__ float wsum[4];
  if (lane == 0) wsum[wid] = part;
  __syncthreads();
  if (tid == 0) beff2[c] = bb[cl] + wsum[0] + wsum[1] + wsum[2] + wsum[3];
}

// ---------------- bf16 MFMA GEMM (m97 2-phase + T2 swizzle + T1) --------------
template <typename OutT>
__global__ __launch_bounds__(256, 5) void gemm_kernel(
    const unsigned short* __restrict__ A, const unsigned short* __restrict__ B,
    const float* __restrict__ bias0, const float* __restrict__ bias1,
    OutT* __restrict__ C0, OutT* __restrict__ C1,
    int M, int K, int NT, int nsplit, int swz) {
  __shared__ __align__(16) unsigned short As[128 * 64];
  __shared__ __align__(16) unsigned short Bs[128 * 64];
  int bid = blockIdx.x;
  if (swz) bid = (bid & 7) * (gridDim.x >> 3) + (bid >> 3);  // XCD-chunked (nwg%8==0)
  int tm = bid / NT, tn = bid % NT;
  int tid = threadIdx.x, wid = tid >> 6, lane = tid & 63;
  int wr = wid >> 1, wc = wid & 1;
  const unsigned short* gA = A + (size_t)(tm * 128) * K;
  const unsigned short* gB = B + (size_t)(tn * 128) * K;
  int srow = wid * 8 + (lane >> 3);
  int scol = ((lane & 7) ^ (lane >> 3)) * 8;   // T2: srow&7 == lane>>3

  f32x4 acc[4][4];
  f32x4 zero = {0.f, 0.f, 0.f, 0.f};
#pragma unroll
  for (int i = 0; i < 4; i++)
#pragma unroll
    for (int j = 0; j < 4; j++) acc[i][j] = zero;

  int KT = K >> 6;
  for (int kt = 0; kt < KT; ++kt) {
    if (kt) __syncthreads();
    {
      const unsigned short* a0 = gA + (size_t)srow * K + kt * 64 + scol;
      const unsigned short* b0 = gB + (size_t)srow * K + kt * 64 + scol;
#pragma unroll
      for (int i = 0; i < 4; i++)
        gload_lds16(a0 + (size_t)i * 32 * K, &As[i * 2048 + wid * 512]);
#pragma unroll
      for (int i = 0; i < 4; i++)
        gload_lds16(b0 + (size_t)i * 32 * K, &Bs[i * 2048 + wid * 512]);
    }
    asm volatile("s_waitcnt vmcnt(0)" ::: "memory");
    __syncthreads();
#pragma unroll
    for (int kk = 0; kk < 2; kk++) {
      int ko = kk * 32 + (lane >> 4) * 8;
      int kosw = ko ^ ((lane & 7) << 3);       // T2 read: r&7 == lane&7
      bf16x8 af[4], bfr[4];
#pragma unroll
      for (int mi = 0; mi < 4; mi++)
        af[mi] = *(const bf16x8*)&As[(wr * 64 + mi * 16 + (lane & 15)) * 64 + kosw];
#pragma unroll
      for (int ni = 0; ni < 4; ni++)
        bfr[ni] = *(const bf16x8*)&Bs[(wc * 64 + ni * 16 + (lane & 15)) * 64 + kosw];
#pragma unroll
      for (int mi = 0; mi < 4; mi++)
#pragma unroll
        for (int ni = 0; ni < 4; ni++)
          acc[mi][ni] = __builtin_amdgcn_mfma_f32_16x16x32_bf16(
              af[mi], bfr[ni], acc[mi][ni], 0, 0, 0);
    }
  }

  int ncol_tile = tn * 128;
  OutT* Cd; const float* bs; int col0;
  if (ncol_tile < nsplit) { Cd = C0; bs = bias0; col0 = ncol_tile; }
  else { Cd = C1; bs = bias1; col0 = ncol_tile - nsplit; }
#pragma unroll
  for (int mi = 0; mi < 4; mi++) {
    int rbase = tm * 128 + wr * 64 + mi * 16 + (lane >> 4) * 4;
#pragma unroll
    for (int ni = 0; ni < 4; ni++) {
      int c = col0 + wc * 64 + ni * 16 + (lane & 15);
      float bv = bs[c];
#pragma unroll
      for (int j = 0; j < 4; j++) {
        int r = rbase + j;
        if (r < M) {
          float v = acc[mi][ni][j] + bv;
          if constexpr (sizeof(OutT) == 2) Cd[(size_t)r * nsplit + c] = f2bf(v);
          else Cd[(size_t)r * nsplit + c] = v;
        }
      }
    }
  }
}

// ---------------- CSR build (self-loop placed first per segment) --------------
__global__ void hist_kernel(const int* __restrict__ dst, int* deg, int E) {
  int e = blockIdx.x * 256 + threadIdx.x;
  if (e < E) atomicAdd(&deg[dst[e]], 1);
}
__global__ __launch_bounds__(1024) void scan1_kernel(
    const int* __restrict__ deg, int* __restrict__ off, int* __restrict__ btot, int n) {
  __shared__ int wsum[16];
  int tid = threadIdx.x, lane = tid & 63, w = tid >> 6;
  int i = blockIdx.x * 1024 + tid;
  int v = (i < n) ? deg[i] + 1 : 0;    // +1 self loop
  int s = v;
#pragma unroll
  for (int d = 1; d < 64; d <<= 1) {
    int t = __shfl_up(s, d);
    if (lane >= d) s += t;
  }
  if (lane == 63) wsum[w] = s;
  __syncthreads();
  if (w == 0 && lane < 16) {
    int t = wsum[lane];
#pragma unroll
    for (int d = 1; d < 16; d <<= 1) {
      int u = __shfl_up(t, d);
      if (lane >= d) t += u;
    }
    wsum[lane] = t;
  }
  __syncthreads();
  int incl = (w ? wsum[w - 1] : 0) + s;
  if (i < n) off[i] = incl - v;               // block-local exclusive
  if (tid == 1023) btot[blockIdx.x] = incl;
}
__global__ void scan2_kernel(const int* __restrict__ btot, int* __restrict__ gbase,
                             int* __restrict__ off, int nb, int n) {
  int lane = threadIdx.x;
  int v = lane < nb ? btot[lane] : 0;
  int s = v;
#pragma unroll
  for (int d = 1; d < 64; d <<= 1) {
    int t = __shfl_up(s, d);
    if (lane >= d) s += t;
  }
  if (lane < nb) gbase[lane] = s - v;
  if (lane == nb - 1) off[n] = s;
}
__global__ __launch_bounds__(1024) void scan3_kernel(
    int* __restrict__ off, int* __restrict__ cursor,
    const int* __restrict__ gbase, int* __restrict__ esrc, int n) {
  int i = blockIdx.x * 1024 + threadIdx.x;
  if (i < n) {
    int v = off[i] + gbase[blockIdx.x];
    off[i] = v;
    cursor[i] = v + 1;    // slot v reserved for self loop
    esrc[v] = i;
  }
}
__global__ void scatter_kernel(const int* __restrict__ src, const int* __restrict__ dst,
                               int* cursor, int* __restrict__ esrc, int E) {
  int e = blockIdx.x * 256 + threadIdx.x;
  if (e < E) {
    int pos = atomicAdd(&cursor[dst[e]], 1);
    esrc[pos] = src[e];
  }
}

// ---------------- GATv2 aggregate: one wave/node, no-max softmax, ILP-2 -------
// Grid covers npad/4 nodes; nodes in [n, npad) write zero rows (pad for GEMM A).
template <int VPL, typename OutT>
__global__ __launch_bounds__(256) void gat_agg_kernel(
    const unsigned short* __restrict__ xl, const unsigned short* __restrict__ xr,
    const float* __restrict__ att, const float* __restrict__ bias,
    const int* __restrict__ off, const int* __restrict__ esrc,
    OutT* __restrict__ out, int n, int do_relu) {
  constexpr int C = VPL * 64;
  using RawT = std::conditional_t<VPL == 8, bf16x8, unsigned int>;
  int node = blockIdx.x * 4 + (threadIdx.x >> 6);
  int lane = threadIdx.x & 63;
  int base = lane * VPL;
  if (node >= n) {
#pragma unroll
    for (int v = 0; v < VPL; v++) out[(size_t)node * C + base + v] = OutT(0);
    return;
  }
  float xrv[VPL], attv[VPL];
#pragma unroll
  for (int v = 0; v < VPL; v++) {
    xrv[v] = bf2f(xr[(size_t)node * C + base + v]);
    attv[v] = att[base + v];
  }
  float s0 = 0.f, s1 = 0.f;
  float acc0[VPL], acc1[VPL];
#pragma unroll
  for (int v = 0; v < VPL; v++) { acc0[v] = 0.f; acc1[v] = 0.f; }
  int e0 = off[node], e1 = off[node + 1];
  int e = e0;
  for (; e + 1 < e1; e += 2) {
    RawT r0 = *(const RawT*)(xl + (size_t)esrc[e] * C + base);
    RawT r1 = *(const RawT*)(xl + (size_t)esrc[e + 1] * C + base);
    float x0[VPL], x1[VPL];
    if constexpr (VPL == 8) {
#pragma unroll
      for (int v = 0; v < 8; v++) { x0[v] = bf2f((unsigned short)r0[v]);
                                    x1[v] = bf2f((unsigned short)r1[v]); }
    } else {
      x0[0] = bf2f((unsigned short)(r0 & 0xffffu)); x0[1] = bf2f((unsigned short)(r0 >> 16));
      x1[0] = bf2f((unsigned short)(r1 & 0xffffu)); x1[1] = bf2f((unsigned short)(r1 >> 16));
    }
    float p0 = 0.f, p1 = 0.f;
#pragma unroll
    for (int v = 0; v < VPL; v++) {
      float t0 = x0[v] + xrv[v]; t0 = t0 > 0.f ? t0 : 0.2f * t0;
      float t1 = x1[v] + xrv[v]; t1 = t1 > 0.f ? t1 : 0.2f * t1;
      p0 += attv[v] * t0;
      p1 += attv[v] * t1;
    }
#pragma unroll
    for (int d2 = 32; d2; d2 >>= 1) { p0 += __shfl_xor(p0, d2); p1 += __shfl_xor(p1, d2); }
    float w0 = __expf(p0), w1 = __expf(p1);
    s0 += w0; s1 += w1;
#pragma unroll
    for (int v = 0; v < VPL; v++) { acc0[v] += w0 * x0[v]; acc1[v] += w1 * x1[v]; }
  }
  if (e < e1) {
    RawT r0 = *(const RawT*)(xl + (size_t)esrc[e] * C + base);
    float x0[VPL];
    if constexpr (VPL == 8) {
#pragma unroll
      for (int v = 0; v < 8; v++) x0[v] = bf2f((unsigned short)r0[v]);
    } else {
      x0[0] = bf2f((unsigned short)(r0 & 0xffffu)); x0[1] = bf2f((unsigned short)(r0 >> 16));
    }
    float p0 = 0.f;
#pragma unroll
    for (int v = 0; v < VPL; v++) {
      float t0 = x0[v] + xrv[v]; t0 = t0 > 0.f ? t0 : 0.2f * t0;
      p0 += attv[v] * t0;
    }
#pragma unroll
    for (int d2 = 32; d2; d2 >>= 1) p0 += __shfl_xor(p0, d2);
    float w0 = __expf(p0);
    s0 += w0;
#pragma unroll
    for (int v = 0; v < VPL; v++) acc0[v] += w0 * x0[v];
  }
  float inv = 1.f / (s0 + s1 + 1e-16f);
#pragma unroll
  for (int v = 0; v < VPL; v++) {
    float o = (acc0[v] + acc1[v]) * inv + bias[base + v];
    if (do_relu) o = fmaxf(o, 0.f);
    if constexpr (sizeof(OutT) == 2) out[(size_t)node * C + base + v] = f2bf(o);
    else out[(size_t)node * C + base + v] = o;
  }
}

// ---------------- BN stats from bf16 h1 ---------------------------------------
__global__ __launch_bounds__(256) void bn_stats_kernel(
    const unsigned short* __restrict__ h1, float* __restrict__ stats, int n) {
  int tid = threadIdx.x;
  int c0 = tid * 2;
  int r0 = blockIdx.x * 128;
  int r1 = r0 + 128 < n ? r0 + 128 : n;
  float s0 = 0, q0 = 0, s1 = 0, q1 = 0;
  for (int r = r0; r < r1; ++r) {
    unsigned u = *(const unsigned*)&h1[(size_t)r * 512 + c0];
    float a = bf2f((unsigned short)(u & 0xffffu));
    float b = bf2f((unsigned short)(u >> 16));
    s0 += a; q0 += a * a; s1 += b; q1 += b * b;
  }
  atomicAdd(&stats[c0], s0);
  atomicAdd(&stats[c0 + 1], s1);
  atomicAdd(&stats[512 + c0], q0);
  atomicAdd(&stats[512 + c0 + 1], q1);
}

// ---------------- launch ----------------
extern "C" void kernel_launch(void* const* d_in, const int* in_sizes, int n_in,
                              void* d_out, int out_size, void* d_ws, size_t ws_size,
                              hipStream_t stream) {
  (void)in_sizes; (void)n_in; (void)out_size; (void)ws_size;
  const float* x      = (const float*)d_in[0];
  const int*   ei     = (const int*)d_in[1];
  const float* conv_w = (const float*)d_in[2];
  const float* conv_b = (const float*)d_in[3];
  const float* W1l    = (const float*)d_in[4];
  const float* b1l    = (const float*)d_in[5];
  const float* W1r    = (const float*)d_in[6];
  const float* b1r    = (const float*)d_in[7];
  const float* att1   = (const float*)d_in[8];
  const float* bias1  = (const float*)d_in[9];
  const float* gamma  = (const float*)d_in[10];
  const float* beta   = (const float*)d_in[11];
  const float* W2l    = (const float*)d_in[12];
  const float* b2l    = (const float*)d_in[13];
  const float* W2r    = (const float*)d_in[14];
  const float* b2r    = (const float*)d_in[15];
  const float* att2   = (const float*)d_in[16];
  const float* bias2  = (const float*)d_in[17];

  char* ws = (char*)d_ws;
  size_t off = 0;
  auto alloc = [&](size_t bytes) {
    size_t r = off;
    off += (bytes + 255) & ~(size_t)255;
    return r;
  };
  size_t o_xb   = alloc((size_t)MPAD * 768 * 2);   // bf16 x (A of GEMM1)
  size_t o_wc1  = alloc((size_t)1024 * 768 * 2);   // Weff^T bf16
  size_t o_wc2  = alloc((size_t)256 * 512 * 2);    // W2eff^T bf16
  size_t o_xl1  = alloc((size_t)NN * 512 * 2);
  size_t o_xr1  = alloc((size_t)NN * 512 * 2);
  size_t o_h1   = alloc((size_t)MPAD * 512 * 2);   // bf16 relu(agg1)
  size_t o_xl2  = alloc((size_t)NN * 128 * 2);
  size_t o_xr2  = alloc((size_t)NN * 128 * 2);
  size_t o_off  = alloc((size_t)(NN + 1) * 4);
  size_t o_cur  = alloc((size_t)NN * 4);
  size_t o_deg  = alloc((size_t)NN * 4);
  size_t o_esrc = alloc((size_t)ETOT * 4);
  size_t o_stats = alloc((size_t)1024 * 4);
  size_t o_scsh  = alloc((size_t)1024 * 4);
  size_t o_beff1 = alloc((size_t)1024 * 4);
  size_t o_beff2 = alloc((size_t)256 * 4);
  size_t o_btot  = alloc((size_t)64 * 4);
  size_t o_gbase = alloc((size_t)64 * 4);

  unsigned short* xb  = (unsigned short*)(ws + o_xb);
  unsigned short* wc1 = (unsigned short*)(ws + o_wc1);
  unsigned short* wc2 = (unsigned short*)(ws + o_wc2);
  unsigned short* xl1 = (unsigned short*)(ws + o_xl1);
  unsigned short* xr1 = (unsigned short*)(ws + o_xr1);
  unsigned short* h1  = (unsigned short*)(ws + o_h1);
  unsigned short* xl2 = (unsigned short*)(ws + o_xl2);
  unsigned short* xr2 = (unsigned short*)(ws + o_xr2);
  int* offp  = (int*)(ws + o_off);
  int* curp  = (int*)(ws + o_cur);
  int* degp  = (int*)(ws + o_deg);
  int* esrc  = (int*)(ws + o_esrc);
  float* stats = (float*)(ws + o_stats);
  float* scsh  = (float*)(ws + o_scsh);
  float* beff1 = (float*)(ws + o_beff1);
  float* beff2 = (float*)(ws + o_beff2);
  int* btot  = (int*)(ws + o_btot);
  int* gbase = (int*)(ws + o_gbase);

  const int* src_raw = ei;
  const int* dst_raw = ei + ERAW;
  float* mu = (float*)d_out;

  zero_init_kernel<<<(NN + 255) / 256, 256, 0, stream>>>(degp, stats, beff1, NN);
  cast_x_kernel<<<(MPAD * 96) / 256, 256, 0, stream>>>(x, xb);
  weff_kernel<<<dim3(32, 4), 256, 0, stream>>>(conv_w, conv_b, W1l, b1l, W1r, b1r, wc1, beff1);

  hist_kernel<<<(ERAW + 255) / 256, 256, 0, stream>>>(dst_raw, degp, ERAW);
  const int NB = (NN + 1023) / 1024;  // 20
  scan1_kernel<<<NB, 1024, 0, stream>>>(degp, offp, btot, NN);
  scan2_kernel<<<1, 64, 0, stream>>>(btot, gbase, offp, NB, NN);
  scan3_kernel<<<NB, 1024, 0, stream>>>(offp, curp, gbase, esrc, NN);
  scatter_kernel<<<(ERAW + 255) / 256, 256, 0, stream>>>(src_raw, dst_raw, curp, esrc, ERAW);

  // layer 1: xl1/xr1 = xb @ Weff + beff1   (conv folded in; K=768)
  gemm_kernel<unsigned short><<<(MPAD / 128) * (1024 / 128), 256, 0, stream>>>(
      xb, wc1, beff1, beff1 + 512, xl1, xr1, NN, 768, 8, 512, 1);
  // grid covers MPAD rows: pad nodes write zero h1 rows (GEMM2 A pad)
  gat_agg_kernel<8, unsigned short><<<MPAD / 4, 256, 0, stream>>>(
      xl1, xr1, att1, bias1, offp, esrc, h1, NN, 1);

  // batchnorm stats + fold into W2
  bn_stats_kernel<<<(NN + 127) / 128, 256, 0, stream>>>(h1, stats, NN);
  bnscale_kernel<<<2, 256, 0, stream>>>(stats, gamma, beta, scsh);
  w2fold_kernel<<<256, 256, 0, stream>>>(scsh, W2l, b2l, W2r, b2r, wc2, beff2);

  // layer 2: xl2/xr2 = h1 @ W2eff + beff2  (BN folded in; K=512)
  gemm_kernel<unsigned short><<<(MPAD / 128) * (256 / 128), 256, 0, stream>>>(
      h1, wc2, beff2, beff2 + 128, xl2, xr2, NN, 512, 2, 128, 0);
  gat_agg_kernel<2, float><<<NN / 4, 256, 0, stream>>>(
      xl2, xr2, att2, bias2, offp, esrc, mu, NN, 0);
}

// Round 6
// 282.273 us; speedup vs baseline: 2.0138x; 1.0563x over previous
//
#include <hip/hip_runtime.h>
#include <cstdint>
#include <cstddef>
#include <type_traits>

static constexpr int NN   = 20000;     // nodes
static constexpr int MPAD = 20096;     // 157 * 128
static constexpr int ERAW = 320000;    // given edges
static constexpr int ETOT = ERAW + NN; // + self loops

typedef __attribute__((ext_vector_type(8))) short bf16x8;
typedef __attribute__((ext_vector_type(8))) unsigned short u16x8;
typedef __attribute__((ext_vector_type(4))) float f32x4;

__device__ __forceinline__ unsigned short f2bf(float f) {
  union { float f; unsigned u; } v; v.f = f;
  unsigned r = v.u + 0x7fffu + ((v.u >> 16) & 1u);
  return (unsigned short)(r >> 16);
}
__device__ __forceinline__ float bf2f(unsigned short u) {
  union { unsigned u; float f; } v; v.u = ((unsigned)u) << 16;
  return v.f;
}

__device__ __forceinline__ void gload_lds16(const void* g, void* l) {
  __builtin_amdgcn_global_load_lds(
      (const __attribute__((address_space(1))) unsigned int*)g,
      (__attribute__((address_space(3))) unsigned int*)l, 16, 0, 0);
}

// ---------------- x fp32 -> bf16 cast + zero-init (fused) ---------------------
__global__ __launch_bounds__(256) void cast_x_kernel(
    const float* __restrict__ x, unsigned short* __restrict__ xb,
    int* __restrict__ degp, float* __restrict__ stats, float* __restrict__ beff1) {
  int i8 = blockIdx.x * 256 + threadIdx.x;   // 8-elem chunk; 96 chunks/row
  if (i8 < NN) degp[i8] = 0;
  if (i8 < 1024) { stats[i8] = 0.f; beff1[i8] = 0.f; }
  size_t base = (size_t)i8 * 8;
  int row = i8 / 96;
  u16x8 o;
  if (row < NN) {
    float4 a = *(const float4*)&x[base];
    float4 b = *(const float4*)&x[base + 4];
    o[0] = f2bf(a.x); o[1] = f2bf(a.y); o[2] = f2bf(a.z); o[3] = f2bf(a.w);
    o[4] = f2bf(b.x); o[5] = f2bf(b.y); o[6] = f2bf(b.z); o[7] = f2bf(b.w);
  } else {
#pragma unroll
    for (int j = 0; j < 8; j++) o[j] = 0;
  }
  *(u16x8*)&xb[base] = o;
}

// ---------------- conv folded into W1: Weff^T[c][k*32+t], beff1[c] ------------
__global__ __launch_bounds__(256) void weff_kernel(
    const float* __restrict__ conv_w, const float* __restrict__ conv_b,
    const float* __restrict__ W1l, const float* __restrict__ b1l,
    const float* __restrict__ W1r, const float* __restrict__ b1r,
    unsigned short* __restrict__ wc1, float* __restrict__ beff1) {
  __shared__ float ws[64 * 24];
  int t = blockIdx.x;                 // 0..31
  int tid = threadIdx.x;
  for (int i = tid; i < 64 * 24; i += 256) ws[i] = conv_w[i];
  __syncthreads();
  int c = blockIdx.y * 256 + tid;     // 0..1023
  const float* W; const float* bb; int cl;
  if (c < 512) { W = W1l; bb = b1l; cl = c; } else { W = W1r; bb = b1r; cl = c - 512; }
  float acc[24];
#pragma unroll
  for (int k = 0; k < 24; k++) acc[k] = 0.f;
  float bacc = (t == 0) ? bb[cl] : 0.f;
  for (int o = 0; o < 64; o += 4) {
    float Wv[4];
#pragma unroll
    for (int j = 0; j < 4; j++) Wv[j] = W[(size_t)((o + j) * 32 + t) * 512 + cl];
#pragma unroll
    for (int j = 0; j < 4; j++) {
      bacc += conv_b[o + j] * Wv[j];
#pragma unroll
      for (int k = 0; k < 24; k++) acc[k] += ws[(o + j) * 24 + k] * Wv[j];
    }
  }
#pragma unroll
  for (int k = 0; k < 24; k++) wc1[(size_t)c * 768 + k * 32 + t] = f2bf(acc[k]);
  atomicAdd(&beff1[c], bacc);
}

// ---------------- BN folded into W2 (parallel; sc/sh computed inline) ---------
__global__ __launch_bounds__(256) void w2fold_kernel(
    const float* __restrict__ stats, const float* __restrict__ gamma,
    const float* __restrict__ beta,
    const float* __restrict__ W2l, const float* __restrict__ b2l,
    const float* __restrict__ W2r, const float* __restrict__ b2r,
    unsigned short* __restrict__ wc2, float* __restrict__ beff2) {
  int c = blockIdx.x;                 // 0..255
  const float* W; const float* bb; int cl;
  if (c < 128) { W = W2l; bb = b2l; cl = c; } else { W = W2r; bb = b2r; cl = c - 128; }
  int tid = threadIdx.x, lane = tid & 63, wid = tid >> 6;
  float part = 0.f;
#pragma unroll
  for (int j = 0; j < 2; j++) {
    int k = tid * 2 + j;
    float mean = stats[k] * (1.f / NN);
    float var = stats[512 + k] * (1.f / NN) - mean * mean;
    float rstd = rsqrtf(var + 1e-5f);
    float sc = gamma[k] * rstd;
    float sh = beta[k] - sc * mean;
    float wv = W[(size_t)k * 128 + cl];
    wc2[(size_t)c * 512 + k] = f2bf(sc * wv);
    part += sh * wv;
  }
#pragma unroll
  for (int d = 32; d; d >>= 1) part += __shfl_xor(part, d);
  __shared__ float wsum[4];
  if (lane == 0) wsum[wid] = part;
  __syncthreads();
  if (tid == 0) beff2[c] = bb[cl] + wsum[0] + wsum[1] + wsum[2] + wsum[3];
}

// ---------------- bf16 MFMA GEMM (m97 2-phase + T2 swizzle + T1) --------------
template <typename OutT>
__global__ __launch_bounds__(256, 5) void gemm_kernel(
    const unsigned short* __restrict__ A, const unsigned short* __restrict__ B,
    const float* __restrict__ bias0, const float* __restrict__ bias1,
    OutT* __restrict__ C0, OutT* __restrict__ C1,
    int M, int K, int NT, int nsplit, int swz) {
  __shared__ __align__(16) unsigned short As[128 * 64];
  __shared__ __align__(16) unsigned short Bs[128 * 64];
  int bid = blockIdx.x;
  if (swz) bid = (bid & 7) * (gridDim.x >> 3) + (bid >> 3);  // XCD-chunked (nwg%8==0)
  int tm = bid / NT, tn = bid % NT;
  int tid = threadIdx.x, wid = tid >> 6, lane = tid & 63;
  int wr = wid >> 1, wc = wid & 1;
  const unsigned short* gA = A + (size_t)(tm * 128) * K;
  const unsigned short* gB = B + (size_t)(tn * 128) * K;
  int srow = wid * 8 + (lane >> 3);
  int scol = ((lane & 7) ^ (lane >> 3)) * 8;   // T2: srow&7 == lane>>3

  f32x4 acc[4][4];
  f32x4 zero = {0.f, 0.f, 0.f, 0.f};
#pragma unroll
  for (int i = 0; i < 4; i++)
#pragma unroll
    for (int j = 0; j < 4; j++) acc[i][j] = zero;

  int KT = K >> 6;
  for (int kt = 0; kt < KT; ++kt) {
    if (kt) __syncthreads();
    {
      const unsigned short* a0 = gA + (size_t)srow * K + kt * 64 + scol;
      const unsigned short* b0 = gB + (size_t)srow * K + kt * 64 + scol;
#pragma unroll
      for (int i = 0; i < 4; i++)
        gload_lds16(a0 + (size_t)i * 32 * K, &As[i * 2048 + wid * 512]);
#pragma unroll
      for (int i = 0; i < 4; i++)
        gload_lds16(b0 + (size_t)i * 32 * K, &Bs[i * 2048 + wid * 512]);
    }
    asm volatile("s_waitcnt vmcnt(0)" ::: "memory");
    __syncthreads();
#pragma unroll
    for (int kk = 0; kk < 2; kk++) {
      int ko = kk * 32 + (lane >> 4) * 8;
      int kosw = ko ^ ((lane & 7) << 3);       // T2 read: r&7 == lane&7
      bf16x8 af[4], bfr[4];
#pragma unroll
      for (int mi = 0; mi < 4; mi++)
        af[mi] = *(const bf16x8*)&As[(wr * 64 + mi * 16 + (lane & 15)) * 64 + kosw];
#pragma unroll
      for (int ni = 0; ni < 4; ni++)
        bfr[ni] = *(const bf16x8*)&Bs[(wc * 64 + ni * 16 + (lane & 15)) * 64 + kosw];
#pragma unroll
      for (int mi = 0; mi < 4; mi++)
#pragma unroll
        for (int ni = 0; ni < 4; ni++)
          acc[mi][ni] = __builtin_amdgcn_mfma_f32_16x16x32_bf16(
              af[mi], bfr[ni], acc[mi][ni], 0, 0, 0);
    }
  }

  int ncol_tile = tn * 128;
  OutT* Cd; const float* bs; int col0;
  if (ncol_tile < nsplit) { Cd = C0; bs = bias0; col0 = ncol_tile; }
  else { Cd = C1; bs = bias1; col0 = ncol_tile - nsplit; }
#pragma unroll
  for (int mi = 0; mi < 4; mi++) {
    int rbase = tm * 128 + wr * 64 + mi * 16 + (lane >> 4) * 4;
#pragma unroll
    for (int ni = 0; ni < 4; ni++) {
      int c = col0 + wc * 64 + ni * 16 + (lane & 15);
      float bv = bs[c];
#pragma unroll
      for (int j = 0; j < 4; j++) {
        int r = rbase + j;
        if (r < M) {
          float v = acc[mi][ni][j] + bv;
          if constexpr (sizeof(OutT) == 2) Cd[(size_t)r * nsplit + c] = f2bf(v);
          else Cd[(size_t)r * nsplit + c] = v;
        }
      }
    }
  }
}

// ---------------- CSR build (self-loop placed first per segment) --------------
__global__ void hist_kernel(const int* __restrict__ dst, int* deg, int E) {
  int e = blockIdx.x * 256 + threadIdx.x;
  if (e < E) atomicAdd(&deg[dst[e]], 1);
}
__global__ __launch_bounds__(1024) void scan1_kernel(
    const int* __restrict__ deg, int* __restrict__ off, int* __restrict__ btot, int n) {
  __shared__ int wsum[16];
  int tid = threadIdx.x, lane = tid & 63, w = tid >> 6;
  int i = blockIdx.x * 1024 + tid;
  int v = (i < n) ? deg[i] + 1 : 0;    // +1 self loop
  int s = v;
#pragma unroll
  for (int d = 1; d < 64; d <<= 1) {
    int t = __shfl_up(s, d);
    if (lane >= d) s += t;
  }
  if (lane == 63) wsum[w] = s;
  __syncthreads();
  if (w == 0 && lane < 16) {
    int t = wsum[lane];
#pragma unroll
    for (int d = 1; d < 16; d <<= 1) {
      int u = __shfl_up(t, d);
      if (lane >= d) t += u;
    }
    wsum[lane] = t;
  }
  __syncthreads();
  int incl = (w ? wsum[w - 1] : 0) + s;
  if (i < n) off[i] = incl - v;               // block-local exclusive
  if (tid == 1023) btot[blockIdx.x] = incl;
}
__global__ void scan2_kernel(const int* __restrict__ btot, int* __restrict__ gbase,
                             int* __restrict__ off, int nb, int n) {
  int lane = threadIdx.x;
  int v = lane < nb ? btot[lane] : 0;
  int s = v;
#pragma unroll
  for (int d = 1; d < 64; d <<= 1) {
    int t = __shfl_up(s, d);
    if (lane >= d) s += t;
  }
  if (lane < nb) gbase[lane] = s - v;
  if (lane == nb - 1) off[n] = s;
}
__global__ __launch_bounds__(1024) void scan3_kernel(
    int* __restrict__ off, int* __restrict__ cursor,
    const int* __restrict__ gbase, int* __restrict__ esrc, int n) {
  int i = blockIdx.x * 1024 + threadIdx.x;
  if (i < n) {
    int v = off[i] + gbase[blockIdx.x];
    off[i] = v;
    cursor[i] = v + 1;    // slot v reserved for self loop
    esrc[v] = i;
  }
}
__global__ void scatter_kernel(const int* __restrict__ src, const int* __restrict__ dst,
                               int* cursor, int* __restrict__ esrc, int E) {
  int e = blockIdx.x * 256 + threadIdx.x;
  if (e < E) {
    int pos = atomicAdd(&cursor[dst[e]], 1);
    esrc[pos] = src[e];
  }
}

// ---------------- GATv2 aggregate: one wave/node, no-max softmax, ILP-4 -------
// Grid covers npad/4 nodes; nodes in [n, npad) write zero rows (pad for GEMM A).
template <int VPL, typename OutT>
__global__ __launch_bounds__(256) void gat_agg_kernel(
    const unsigned short* __restrict__ xl, const unsigned short* __restrict__ xr,
    const float* __restrict__ att, const float* __restrict__ bias,
    const int* __restrict__ off, const int* __restrict__ esrc,
    OutT* __restrict__ out, int n, int do_relu) {
  constexpr int C = VPL * 64;
  using RawT = std::conditional_t<VPL == 8, uint4, unsigned int>;
  int node = blockIdx.x * 4 + (threadIdx.x >> 6);
  int lane = threadIdx.x & 63;
  int base = lane * VPL;
  if (node >= n) {
#pragma unroll
    for (int v = 0; v < VPL; v++) out[(size_t)node * C + base + v] = OutT(0);
    return;
  }
  float xrv[VPL], attv[VPL];
#pragma unroll
  for (int v = 0; v < VPL; v++) {
    xrv[v] = bf2f(xr[(size_t)node * C + base + v]);
    attv[v] = att[base + v];
  }
  auto cvt = [](RawT r, float* xv) {
    if constexpr (VPL == 8) {
      unsigned u[4] = {r.x, r.y, r.z, r.w};
#pragma unroll
      for (int i = 0; i < 4; i++) {
        xv[2 * i]     = __uint_as_float(u[i] << 16);
        xv[2 * i + 1] = __uint_as_float(u[i] & 0xffff0000u);
      }
    } else {
      xv[0] = __uint_as_float(r << 16);
      xv[1] = __uint_as_float(r & 0xffff0000u);
    }
  };
  auto score = [&](const float* xv) {
    float p = 0.f;
#pragma unroll
    for (int v = 0; v < VPL; v++) {
      float t = xv[v] + xrv[v];
      p += attv[v] * fmaxf(t, 0.2f * t);   // leaky_relu(0.2) = max(t, 0.2t)
    }
    return p;
  };
  float s0 = 0.f, s1 = 0.f;
  float acc0[VPL], acc1[VPL];
#pragma unroll
  for (int v = 0; v < VPL; v++) { acc0[v] = 0.f; acc1[v] = 0.f; }
  int e0 = off[node], e1 = off[node + 1];
  int e = e0;
  for (; e + 3 < e1; e += 4) {
    int s0i = esrc[e], s1i = esrc[e + 1], s2i = esrc[e + 2], s3i = esrc[e + 3];
    RawT r0 = *(const RawT*)(xl + (size_t)s0i * C + base);
    RawT r1 = *(const RawT*)(xl + (size_t)s1i * C + base);
    RawT r2 = *(const RawT*)(xl + (size_t)s2i * C + base);
    RawT r3 = *(const RawT*)(xl + (size_t)s3i * C + base);
    float x0[VPL], x1[VPL], x2[VPL], x3[VPL];
    cvt(r0, x0); cvt(r1, x1); cvt(r2, x2); cvt(r3, x3);
    float p0 = score(x0), p1 = score(x1), p2 = score(x2), p3 = score(x3);
#pragma unroll
    for (int d2 = 32; d2; d2 >>= 1) {
      p0 += __shfl_xor(p0, d2); p1 += __shfl_xor(p1, d2);
      p2 += __shfl_xor(p2, d2); p3 += __shfl_xor(p3, d2);
    }
    float w0 = __expf(p0), w1 = __expf(p1), w2 = __expf(p2), w3 = __expf(p3);
    s0 += w0 + w2; s1 += w1 + w3;
#pragma unroll
    for (int v = 0; v < VPL; v++) {
      acc0[v] += w0 * x0[v] + w2 * x2[v];
      acc1[v] += w1 * x1[v] + w3 * x3[v];
    }
  }
  for (; e < e1; ++e) {
    RawT r0 = *(const RawT*)(xl + (size_t)esrc[e] * C + base);
    float x0[VPL];
    cvt(r0, x0);
    float p0 = score(x0);
#pragma unroll
    for (int d2 = 32; d2; d2 >>= 1) p0 += __shfl_xor(p0, d2);
    float w0 = __expf(p0);
    s0 += w0;
#pragma unroll
    for (int v = 0; v < VPL; v++) acc0[v] += w0 * x0[v];
  }
  float inv = 1.f / (s0 + s1 + 1e-16f);
#pragma unroll
  for (int v = 0; v < VPL; v++) {
    float o = (acc0[v] + acc1[v]) * inv + bias[base + v];
    if (do_relu) o = fmaxf(o, 0.f);
    if constexpr (sizeof(OutT) == 2) out[(size_t)node * C + base + v] = f2bf(o);
    else out[(size_t)node * C + base + v] = o;
  }
}

// ---------------- BN stats from bf16 h1 ---------------------------------------
__global__ __launch_bounds__(256) void bn_stats_kernel(
    const unsigned short* __restrict__ h1, float* __restrict__ stats, int n) {
  int tid = threadIdx.x;
  int c0 = tid * 2;
  int r0 = blockIdx.x * 128;
  int r1 = r0 + 128 < n ? r0 + 128 : n;
  float s0 = 0, q0 = 0, s1 = 0, q1 = 0;
  for (int r = r0; r < r1; ++r) {
    unsigned u = *(const unsigned*)&h1[(size_t)r * 512 + c0];
    float a = __uint_as_float(u << 16);
    float b = __uint_as_float(u & 0xffff0000u);
    s0 += a; q0 += a * a; s1 += b; q1 += b * b;
  }
  atomicAdd(&stats[c0], s0);
  atomicAdd(&stats[c0 + 1], s1);
  atomicAdd(&stats[512 + c0], q0);
  atomicAdd(&stats[512 + c0 + 1], q1);
}

// ---------------- launch ----------------
extern "C" void kernel_launch(void* const* d_in, const int* in_sizes, int n_in,
                              void* d_out, int out_size, void* d_ws, size_t ws_size,
                              hipStream_t stream) {
  (void)in_sizes; (void)n_in; (void)out_size; (void)ws_size;
  const float* x      = (const float*)d_in[0];
  const int*   ei     = (const int*)d_in[1];
  const float* conv_w = (const float*)d_in[2];
  const float* conv_b = (const float*)d_in[3];
  const float* W1l    = (const float*)d_in[4];
  const float* b1l    = (const float*)d_in[5];
  const float* W1r    = (const float*)d_in[6];
  const float* b1r    = (const float*)d_in[7];
  const float* att1   = (const float*)d_in[8];
  const float* bias1  = (const float*)d_in[9];
  const float* gamma  = (const float*)d_in[10];
  const float* beta   = (const float*)d_in[11];
  const float* W2l    = (const float*)d_in[12];
  const float* b2l    = (const float*)d_in[13];
  const float* W2r    = (const float*)d_in[14];
  const float* b2r    = (const float*)d_in[15];
  const float* att2   = (const float*)d_in[16];
  const float* bias2  = (const float*)d_in[17];

  char* ws = (char*)d_ws;
  size_t off = 0;
  auto alloc = [&](size_t bytes) {
    size_t r = off;
    off += (bytes + 255) & ~(size_t)255;
    return r;
  };
  size_t o_xb   = alloc((size_t)MPAD * 768 * 2);   // bf16 x (A of GEMM1)
  size_t o_wc1  = alloc((size_t)1024 * 768 * 2);   // Weff^T bf16
  size_t o_wc2  = alloc((size_t)256 * 512 * 2);    // W2eff^T bf16
  size_t o_xl1  = alloc((size_t)NN * 512 * 2);
  size_t o_xr1  = alloc((size_t)NN * 512 * 2);
  size_t o_h1   = alloc((size_t)MPAD * 512 * 2);   // bf16 relu(agg1)
  size_t o_xl2  = alloc((size_t)NN * 128 * 2);
  size_t o_xr2  = alloc((size_t)NN * 128 * 2);
  size_t o_off  = alloc((size_t)(NN + 1) * 4);
  size_t o_cur  = alloc((size_t)NN * 4);
  size_t o_deg  = alloc((size_t)NN * 4);
  size_t o_esrc = alloc((size_t)ETOT * 4);
  size_t o_stats = alloc((size_t)1024 * 4);
  size_t o_beff1 = alloc((size_t)1024 * 4);
  size_t o_beff2 = alloc((size_t)256 * 4);
  size_t o_btot  = alloc((size_t)64 * 4);
  size_t o_gbase = alloc((size_t)64 * 4);

  unsigned short* xb  = (unsigned short*)(ws + o_xb);
  unsigned short* wc1 = (unsigned short*)(ws + o_wc1);
  unsigned short* wc2 = (unsigned short*)(ws + o_wc2);
  unsigned short* xl1 = (unsigned short*)(ws + o_xl1);
  unsigned short* xr1 = (unsigned short*)(ws + o_xr1);
  unsigned short* h1  = (unsigned short*)(ws + o_h1);
  unsigned short* xl2 = (unsigned short*)(ws + o_xl2);
  unsigned short* xr2 = (unsigned short*)(ws + o_xr2);
  int* offp  = (int*)(ws + o_off);
  int* curp  = (int*)(ws + o_cur);
  int* degp  = (int*)(ws + o_deg);
  int* esrc  = (int*)(ws + o_esrc);
  float* stats = (float*)(ws + o_stats);
  float* beff1 = (float*)(ws + o_beff1);
  float* beff2 = (float*)(ws + o_beff2);
  int* btot  = (int*)(ws + o_btot);
  int* gbase = (int*)(ws + o_gbase);

  const int* src_raw = ei;
  const int* dst_raw = ei + ERAW;
  float* mu = (float*)d_out;

  cast_x_kernel<<<(MPAD * 96) / 256, 256, 0, stream>>>(x, xb, degp, stats, beff1);
  weff_kernel<<<dim3(32, 4), 256, 0, stream>>>(conv_w, conv_b, W1l, b1l, W1r, b1r, wc1, beff1);

  hist_kernel<<<(ERAW + 255) / 256, 256, 0, stream>>>(dst_raw, degp, ERAW);
  const int NB = (NN + 1023) / 1024;  // 20
  scan1_kernel<<<NB, 1024, 0, stream>>>(degp, offp, btot, NN);
  scan2_kernel<<<1, 64, 0, stream>>>(btot, gbase, offp, NB, NN);
  scan3_kernel<<<NB, 1024, 0, stream>>>(offp, curp, gbase, esrc, NN);
  scatter_kernel<<<(ERAW + 255) / 256, 256, 0, stream>>>(src_raw, dst_raw, curp, esrc, ERAW);

  // layer 1: xl1/xr1 = xb @ Weff + beff1   (conv folded in; K=768)
  gemm_kernel<unsigned short><<<(MPAD / 128) * (1024 / 128), 256, 0, stream>>>(
      xb, wc1, beff1, beff1 + 512, xl1, xr1, NN, 768, 8, 512, 1);
  // grid covers MPAD rows: pad nodes write zero h1 rows (GEMM2 A pad)
  gat_agg_kernel<8, unsigned short><<<MPAD / 4, 256, 0, stream>>>(
      xl1, xr1, att1, bias1, offp, esrc, h1, NN, 1);

  // batchnorm stats + fold into W2
  bn_stats_kernel<<<(NN + 127) / 128, 256, 0, stream>>>(h1, stats, NN);
  w2fold_kernel<<<256, 256, 0, stream>>>(stats, gamma, beta, W2l, b2l, W2r, b2r, wc2, beff2);

  // layer 2: xl2/xr2 = h1 @ W2eff + beff2  (BN folded in; K=512)
  gemm_kernel<unsigned short><<<(MPAD / 128) * (256 / 128), 256, 0, stream>>>(
      h1, wc2, beff2, beff2 + 128, xl2, xr2, NN, 512, 2, 128, 0);
  gat_agg_kernel<2, float><<<NN / 4, 256, 0, stream>>>(
      xl2, xr2, att2, bias2, offp, esrc, mu, NN, 0);
}

// Round 7
// 266.742 us; speedup vs baseline: 2.1310x; 1.0582x over previous
//
#include <hip/hip_runtime.h>
#include <cstdint>
#include <cstddef>
#include <type_traits>

static constexpr int NN   = 20000;     // nodes
static constexpr int MPAD = 20096;     // 157 * 128
static constexpr int ERAW = 320000;    // given edges
static constexpr int ETOT = ERAW + NN; // + self loops

typedef __attribute__((ext_vector_type(8))) short bf16x8;
typedef __attribute__((ext_vector_type(8))) unsigned short u16x8;
typedef __attribute__((ext_vector_type(4))) float f32x4;

__device__ __forceinline__ unsigned short f2bf(float f) {
  union { float f; unsigned u; } v; v.f = f;
  unsigned r = v.u + 0x7fffu + ((v.u >> 16) & 1u);
  return (unsigned short)(r >> 16);
}
__device__ __forceinline__ float bf2f(unsigned short u) {
  union { unsigned u; float f; } v; v.u = ((unsigned)u) << 16;
  return v.f;
}

__device__ __forceinline__ void gload_lds16(const void* g, void* l) {
  __builtin_amdgcn_global_load_lds(
      (const __attribute__((address_space(1))) unsigned int*)g,
      (__attribute__((address_space(3))) unsigned int*)l, 16, 0, 0);
}

// ---------------- x fp32 -> bf16 cast + zero-init (fused) ---------------------
__global__ __launch_bounds__(256) void cast_x_kernel(
    const float* __restrict__ x, unsigned short* __restrict__ xb,
    int* __restrict__ degp, float* __restrict__ stats, float* __restrict__ beff1) {
  int i8 = blockIdx.x * 256 + threadIdx.x;   // 8-elem chunk; 96 chunks/row
  if (i8 < NN) degp[i8] = 0;
  if (i8 < 1024) { stats[i8] = 0.f; beff1[i8] = 0.f; }
  size_t base = (size_t)i8 * 8;
  int row = i8 / 96;
  u16x8 o;
  if (row < NN) {
    float4 a = *(const float4*)&x[base];
    float4 b = *(const float4*)&x[base + 4];
    o[0] = f2bf(a.x); o[1] = f2bf(a.y); o[2] = f2bf(a.z); o[3] = f2bf(a.w);
    o[4] = f2bf(b.x); o[5] = f2bf(b.y); o[6] = f2bf(b.z); o[7] = f2bf(b.w);
  } else {
#pragma unroll
    for (int j = 0; j < 8; j++) o[j] = 0;
  }
  *(u16x8*)&xb[base] = o;
}

// ---------------- conv folded into W1: Weff^T[c][k*32+t], beff1[c] ------------
// grid (32 t, 8 c-chunks); thread pair (c, half) splits the o-loop 32/32.
__global__ __launch_bounds__(256) void weff_kernel(
    const float* __restrict__ conv_w, const float* __restrict__ conv_b,
    const float* __restrict__ W1l, const float* __restrict__ b1l,
    const float* __restrict__ W1r, const float* __restrict__ b1r,
    unsigned short* __restrict__ wc1, float* __restrict__ beff1) {
  __shared__ float ws[64 * 24];
  int t = blockIdx.x;                 // 0..31
  int tid = threadIdx.x;
  for (int i = tid; i < 64 * 24; i += 256) ws[i] = conv_w[i];
  __syncthreads();
  int c = blockIdx.y * 128 + (tid >> 1);   // 0..1023
  int half = tid & 1;
  const float* W; const float* bb; int cl;
  if (c < 512) { W = W1l; bb = b1l; cl = c; } else { W = W1r; bb = b1r; cl = c - 512; }
  float acc[24];
#pragma unroll
  for (int k = 0; k < 24; k++) acc[k] = 0.f;
  float bacc = (t == 0 && half == 0) ? bb[cl] : 0.f;
  for (int o = half * 32; o < half * 32 + 32; o += 4) {
    float Wv[4];
#pragma unroll
    for (int j = 0; j < 4; j++) Wv[j] = W[(size_t)((o + j) * 32 + t) * 512 + cl];
#pragma unroll
    for (int j = 0; j < 4; j++) {
      bacc += conv_b[o + j] * Wv[j];
#pragma unroll
      for (int k = 0; k < 24; k++) acc[k] += ws[(o + j) * 24 + k] * Wv[j];
    }
  }
#pragma unroll
  for (int k = 0; k < 24; k++) acc[k] += __shfl_xor(acc[k], 1);
  bacc += __shfl_xor(bacc, 1);
  if (half == 0) {
#pragma unroll
    for (int k = 0; k < 24; k++) wc1[(size_t)c * 768 + k * 32 + t] = f2bf(acc[k]);
    atomicAdd(&beff1[c], bacc);
  }
}

// ---------------- BN folded into W2 (parallel; sc/sh computed inline) ---------
__global__ __launch_bounds__(256) void w2fold_kernel(
    const float* __restrict__ stats, const float* __restrict__ gamma,
    const float* __restrict__ beta,
    const float* __restrict__ W2l, const float* __restrict__ b2l,
    const float* __restrict__ W2r, const float* __restrict__ b2r,
    unsigned short* __restrict__ wc2, float* __restrict__ beff2) {
  int c = blockIdx.x;                 // 0..255
  const float* W; const float* bb; int cl;
  if (c < 128) { W = W2l; bb = b2l; cl = c; } else { W = W2r; bb = b2r; cl = c - 128; }
  int tid = threadIdx.x, lane = tid & 63, wid = tid >> 6;
  float part = 0.f;
#pragma unroll
  for (int j = 0; j < 2; j++) {
    int k = tid * 2 + j;
    float mean = stats[k] * (1.f / NN);
    float var = stats[512 + k] * (1.f / NN) - mean * mean;
    float rstd = rsqrtf(var + 1e-5f);
    float sc = gamma[k] * rstd;
    float sh = beta[k] - sc * mean;
    float wv = W[(size_t)k * 128 + cl];
    wc2[(size_t)c * 512 + k] = f2bf(sc * wv);
    part += sh * wv;
  }
#pragma unroll
  for (int d = 32; d; d >>= 1) part += __shfl_xor(part, d);
  __shared__ float wsum[4];
  if (lane == 0) wsum[wid] = part;
  __syncthreads();
  if (tid == 0) beff2[c] = bb[cl] + wsum[0] + wsum[1] + wsum[2] + wsum[3];
}

// ---------------- bf16 MFMA GEMM (m97 2-phase + T2 swizzle + T1) --------------
template <typename OutT>
__global__ __launch_bounds__(256, 5) void gemm_kernel(
    const unsigned short* __restrict__ A, const unsigned short* __restrict__ B,
    const float* __restrict__ bias0, const float* __restrict__ bias1,
    OutT* __restrict__ C0, OutT* __restrict__ C1,
    int M, int K, int NT, int nsplit, int swz) {
  __shared__ __align__(16) unsigned short As[128 * 64];
  __shared__ __align__(16) unsigned short Bs[128 * 64];
  int bid = blockIdx.x;
  if (swz) bid = (bid & 7) * (gridDim.x >> 3) + (bid >> 3);  // XCD-chunked (nwg%8==0)
  int tm = bid / NT, tn = bid % NT;
  int tid = threadIdx.x, wid = tid >> 6, lane = tid & 63;
  int wr = wid >> 1, wc = wid & 1;
  const unsigned short* gA = A + (size_t)(tm * 128) * K;
  const unsigned short* gB = B + (size_t)(tn * 128) * K;
  int srow = wid * 8 + (lane >> 3);
  int scol = ((lane & 7) ^ (lane >> 3)) * 8;   // T2: srow&7 == lane>>3

  f32x4 acc[4][4];
  f32x4 zero = {0.f, 0.f, 0.f, 0.f};
#pragma unroll
  for (int i = 0; i < 4; i++)
#pragma unroll
    for (int j = 0; j < 4; j++) acc[i][j] = zero;

  int KT = K >> 6;
  for (int kt = 0; kt < KT; ++kt) {
    if (kt) __syncthreads();
    {
      const unsigned short* a0 = gA + (size_t)srow * K + kt * 64 + scol;
      const unsigned short* b0 = gB + (size_t)srow * K + kt * 64 + scol;
#pragma unroll
      for (int i = 0; i < 4; i++)
        gload_lds16(a0 + (size_t)i * 32 * K, &As[i * 2048 + wid * 512]);
#pragma unroll
      for (int i = 0; i < 4; i++)
        gload_lds16(b0 + (size_t)i * 32 * K, &Bs[i * 2048 + wid * 512]);
    }
    asm volatile("s_waitcnt vmcnt(0)" ::: "memory");
    __syncthreads();
#pragma unroll
    for (int kk = 0; kk < 2; kk++) {
      int ko = kk * 32 + (lane >> 4) * 8;
      int kosw = ko ^ ((lane & 7) << 3);       // T2 read: r&7 == lane&7
      bf16x8 af[4], bfr[4];
#pragma unroll
      for (int mi = 0; mi < 4; mi++)
        af[mi] = *(const bf16x8*)&As[(wr * 64 + mi * 16 + (lane & 15)) * 64 + kosw];
#pragma unroll
      for (int ni = 0; ni < 4; ni++)
        bfr[ni] = *(const bf16x8*)&Bs[(wc * 64 + ni * 16 + (lane & 15)) * 64 + kosw];
#pragma unroll
      for (int mi = 0; mi < 4; mi++)
#pragma unroll
        for (int ni = 0; ni < 4; ni++)
          acc[mi][ni] = __builtin_amdgcn_mfma_f32_16x16x32_bf16(
              af[mi], bfr[ni], acc[mi][ni], 0, 0, 0);
    }
  }

  int ncol_tile = tn * 128;
  OutT* Cd; const float* bs; int col0;
  if (ncol_tile < nsplit) { Cd = C0; bs = bias0; col0 = ncol_tile; }
  else { Cd = C1; bs = bias1; col0 = ncol_tile - nsplit; }
#pragma unroll
  for (int mi = 0; mi < 4; mi++) {
    int rbase = tm * 128 + wr * 64 + mi * 16 + (lane >> 4) * 4;
#pragma unroll
    for (int ni = 0; ni < 4; ni++) {
      int c = col0 + wc * 64 + ni * 16 + (lane & 15);
      float bv = bs[c];
#pragma unroll
      for (int j = 0; j < 4; j++) {
        int r = rbase + j;
        if (r < M) {
          float v = acc[mi][ni][j] + bv;
          if constexpr (sizeof(OutT) == 2) Cd[(size_t)r * nsplit + c] = f2bf(v);
          else Cd[(size_t)r * nsplit + c] = v;
        }
      }
    }
  }
}

// ---------------- CSR build (self-loop placed first per segment) --------------
__global__ void hist_kernel(const int* __restrict__ dst, int* deg, int E) {
  int e = blockIdx.x * 256 + threadIdx.x;
  if (e < E) atomicAdd(&deg[dst[e]], 1);
}
__global__ __launch_bounds__(1024) void scan1_kernel(
    const int* __restrict__ deg, int* __restrict__ off, int* __restrict__ btot, int n) {
  __shared__ int wsum[16];
  int tid = threadIdx.x, lane = tid & 63, w = tid >> 6;
  int i = blockIdx.x * 1024 + tid;
  int v = (i < n) ? deg[i] + 1 : 0;    // +1 self loop
  int s = v;
#pragma unroll
  for (int d = 1; d < 64; d <<= 1) {
    int t = __shfl_up(s, d);
    if (lane >= d) s += t;
  }
  if (lane == 63) wsum[w] = s;
  __syncthreads();
  if (w == 0 && lane < 16) {
    int t = wsum[lane];
#pragma unroll
    for (int d = 1; d < 16; d <<= 1) {
      int u = __shfl_up(t, d);
      if (lane >= d) t += u;
    }
    wsum[lane] = t;
  }
  __syncthreads();
  int incl = (w ? wsum[w - 1] : 0) + s;
  if (i < n) off[i] = incl - v;               // block-local exclusive
  if (tid == 1023) btot[blockIdx.x] = incl;
}
__global__ void scan2_kernel(const int* __restrict__ btot, int* __restrict__ gbase,
                             int* __restrict__ off, int nb, int n) {
  int lane = threadIdx.x;
  int v = lane < nb ? btot[lane] : 0;
  int s = v;
#pragma unroll
  for (int d = 1; d < 64; d <<= 1) {
    int t = __shfl_up(s, d);
    if (lane >= d) s += t;
  }
  if (lane < nb) gbase[lane] = s - v;
  if (lane == nb - 1) off[n] = s;
}
__global__ __launch_bounds__(1024) void scan3_kernel(
    int* __restrict__ off, int* __restrict__ cursor,
    const int* __restrict__ gbase, int* __restrict__ esrc, int n) {
  int i = blockIdx.x * 1024 + threadIdx.x;
  if (i < n) {
    int v = off[i] + gbase[blockIdx.x];
    off[i] = v;
    cursor[i] = v + 1;    // slot v reserved for self loop
    esrc[v] = i;
  }
}
__global__ void scatter_kernel(const int* __restrict__ src, const int* __restrict__ dst,
                               int* cursor, int* __restrict__ esrc, int E) {
  int e = blockIdx.x * 256 + threadIdx.x;
  if (e < E) {
    int pos = atomicAdd(&cursor[dst[e]], 1);
    esrc[pos] = src[e];
  }
}

// ---------------- GATv2 aggregate: wave/node, packed 4-way butterfly ----------
// Grid covers npad/4 nodes; nodes in [n, npad) write zero rows (pad for GEMM A).
template <int VPL, typename OutT>
__global__ __launch_bounds__(256) void gat_agg_kernel(
    const unsigned short* __restrict__ xl, const unsigned short* __restrict__ xr,
    const float* __restrict__ att, const float* __restrict__ bias,
    const int* __restrict__ off, const int* __restrict__ esrc,
    OutT* __restrict__ out, int n, int do_relu) {
  constexpr int C = VPL * 64;
  using RawT = std::conditional_t<VPL == 8, uint4, unsigned int>;
  int node = blockIdx.x * 4 + (threadIdx.x >> 6);
  int lane = threadIdx.x & 63;
  int base = lane * VPL;
  if (node >= n) {
#pragma unroll
    for (int v = 0; v < VPL; v++) out[(size_t)node * C + base + v] = OutT(0);
    return;
  }
  float xrv[VPL], attv[VPL];
#pragma unroll
  for (int v = 0; v < VPL; v++) {
    xrv[v] = bf2f(xr[(size_t)node * C + base + v]);
    attv[v] = att[base + v];
  }
  auto cvt = [](RawT r, float* xv) {
    if constexpr (VPL == 8) {
      unsigned u[4] = {r.x, r.y, r.z, r.w};
#pragma unroll
      for (int i = 0; i < 4; i++) {
        xv[2 * i]     = __uint_as_float(u[i] << 16);
        xv[2 * i + 1] = __uint_as_float(u[i] & 0xffff0000u);
      }
    } else {
      xv[0] = __uint_as_float(r << 16);
      xv[1] = __uint_as_float(r & 0xffff0000u);
    }
  };
  auto score = [&](const float* xv) {
    float p = 0.f;
#pragma unroll
    for (int v = 0; v < VPL; v++) {
      float t = xv[v] + xrv[v];
      p += attv[v] * fmaxf(t, 0.2f * t);   // leaky_relu(0.2) = max(t, 0.2t)
    }
    return p;
  };
  float s0 = 0.f, s1 = 0.f;
  float acc0[VPL], acc1[VPL];
#pragma unroll
  for (int v = 0; v < VPL; v++) { acc0[v] = 0.f; acc1[v] = 0.f; }
  int e0 = off[node], e1 = off[node + 1];
  int e = e0;
  for (; e + 3 < e1; e += 4) {
    int s0i = esrc[e], s1i = esrc[e + 1], s2i = esrc[e + 2], s3i = esrc[e + 3];
    RawT r0 = *(const RawT*)(xl + (size_t)s0i * C + base);
    RawT r1 = *(const RawT*)(xl + (size_t)s1i * C + base);
    RawT r2 = *(const RawT*)(xl + (size_t)s2i * C + base);
    RawT r3 = *(const RawT*)(xl + (size_t)s3i * C + base);
    float x0[VPL], x1[VPL], x2[VPL], x3[VPL];
    cvt(r0, x0); cvt(r1, x1); cvt(r2, x2); cvt(r3, x3);
    float p0 = score(x0), p1 = score(x1), p2 = score(x2), p3 = score(x3);
    // packed 4-value butterfly: one tree instead of four.
    p0 += __shfl_xor(p0, 32); p1 += __shfl_xor(p1, 32);
    p2 += __shfl_xor(p2, 32); p3 += __shfl_xor(p3, 32);
    float a = (lane & 32) ? p1 : p0;
    float b = (lane & 32) ? p3 : p2;
    a += __shfl_xor(a, 16); b += __shfl_xor(b, 16);
    float cpk = (lane & 16) ? b : a;
    cpk += __shfl_xor(cpk, 8); cpk += __shfl_xor(cpk, 4);
    cpk += __shfl_xor(cpk, 2); cpk += __shfl_xor(cpk, 1);
    // lanes 0-15:P0, 16-31:P2, 32-47:P1, 48-63:P3
    float w = __expf(cpk);
    float w0 = __shfl(w, 0),  w2 = __shfl(w, 16);
    float w1 = __shfl(w, 32), w3 = __shfl(w, 48);
    s0 += w0 + w2; s1 += w1 + w3;
#pragma unroll
    for (int v = 0; v < VPL; v++) {
      acc0[v] += w0 * x0[v] + w2 * x2[v];
      acc1[v] += w1 * x1[v] + w3 * x3[v];
    }
  }
  for (; e < e1; ++e) {
    RawT r0 = *(const RawT*)(xl + (size_t)esrc[e] * C + base);
    float x0[VPL];
    cvt(r0, x0);
    float p0 = score(x0);
#pragma unroll
    for (int d2 = 32; d2; d2 >>= 1) p0 += __shfl_xor(p0, d2);
    float w0 = __expf(p0);
    s0 += w0;
#pragma unroll
    for (int v = 0; v < VPL; v++) acc0[v] += w0 * x0[v];
  }
  float inv = 1.f / (s0 + s1 + 1e-16f);
#pragma unroll
  for (int v = 0; v < VPL; v++) {
    float o = (acc0[v] + acc1[v]) * inv + bias[base + v];
    if (do_relu) o = fmaxf(o, 0.f);
    if constexpr (sizeof(OutT) == 2) out[(size_t)node * C + base + v] = f2bf(o);
    else out[(size_t)node * C + base + v] = o;
  }
}

// ---------------- BN stats from bf16 h1 ---------------------------------------
__global__ __launch_bounds__(256) void bn_stats_kernel(
    const unsigned short* __restrict__ h1, float* __restrict__ stats, int n) {
  int tid = threadIdx.x;
  int c0 = tid * 2;
  int r0 = blockIdx.x * 64;
  int r1 = r0 + 64 < n ? r0 + 64 : n;
  float s0 = 0, q0 = 0, s1 = 0, q1 = 0;
  for (int r = r0; r < r1; ++r) {
    unsigned u = *(const unsigned*)&h1[(size_t)r * 512 + c0];
    float a = __uint_as_float(u << 16);
    float b = __uint_as_float(u & 0xffff0000u);
    s0 += a; q0 += a * a; s1 += b; q1 += b * b;
  }
  atomicAdd(&stats[c0], s0);
  atomicAdd(&stats[c0 + 1], s1);
  atomicAdd(&stats[512 + c0], q0);
  atomicAdd(&stats[512 + c0 + 1], q1);
}

// ---------------- launch ----------------
extern "C" void kernel_launch(void* const* d_in, const int* in_sizes, int n_in,
                              void* d_out, int out_size, void* d_ws, size_t ws_size,
                              hipStream_t stream) {
  (void)in_sizes; (void)n_in; (void)out_size; (void)ws_size;
  const float* x      = (const float*)d_in[0];
  const int*   ei     = (const int*)d_in[1];
  const float* conv_w = (const float*)d_in[2];
  const float* conv_b = (const float*)d_in[3];
  const float* W1l    = (const float*)d_in[4];
  const float* b1l    = (const float*)d_in[5];
  const float* W1r    = (const float*)d_in[6];
  const float* b1r    = (const float*)d_in[7];
  const float* att1   = (const float*)d_in[8];
  const float* bias1  = (const float*)d_in[9];
  const float* gamma  = (const float*)d_in[10];
  const float* beta   = (const float*)d_in[11];
  const float* W2l    = (const float*)d_in[12];
  const float* b2l    = (const float*)d_in[13];
  const float* W2r    = (const float*)d_in[14];
  const float* b2r    = (const float*)d_in[15];
  const float* att2   = (const float*)d_in[16];
  const float* bias2  = (const float*)d_in[17];

  char* ws = (char*)d_ws;
  size_t off = 0;
  auto alloc = [&](size_t bytes) {
    size_t r = off;
    off += (bytes + 255) & ~(size_t)255;
    return r;
  };
  size_t o_xb   = alloc((size_t)MPAD * 768 * 2);   // bf16 x (A of GEMM1)
  size_t o_wc1  = alloc((size_t)1024 * 768 * 2);   // Weff^T bf16
  size_t o_wc2  = alloc((size_t)256 * 512 * 2);    // W2eff^T bf16
  size_t o_xl1  = alloc((size_t)NN * 512 * 2);
  size_t o_xr1  = alloc((size_t)NN * 512 * 2);
  size_t o_h1   = alloc((size_t)MPAD * 512 * 2);   // bf16 relu(agg1)
  size_t o_xl2  = alloc((size_t)NN * 128 * 2);
  size_t o_xr2  = alloc((size_t)NN * 128 * 2);
  size_t o_off  = alloc((size_t)(NN + 1) * 4);
  size_t o_cur  = alloc((size_t)NN * 4);
  size_t o_deg  = alloc((size_t)NN * 4);
  size_t o_esrc = alloc((size_t)ETOT * 4);
  size_t o_stats = alloc((size_t)1024 * 4);
  size_t o_beff1 = alloc((size_t)1024 * 4);
  size_t o_beff2 = alloc((size_t)256 * 4);
  size_t o_btot  = alloc((size_t)64 * 4);
  size_t o_gbase = alloc((size_t)64 * 4);

  unsigned short* xb  = (unsigned short*)(ws + o_xb);
  unsigned short* wc1 = (unsigned short*)(ws + o_wc1);
  unsigned short* wc2 = (unsigned short*)(ws + o_wc2);
  unsigned short* xl1 = (unsigned short*)(ws + o_xl1);
  unsigned short* xr1 = (unsigned short*)(ws + o_xr1);
  unsigned short* h1  = (unsigned short*)(ws + o_h1);
  unsigned short* xl2 = (unsigned short*)(ws + o_xl2);
  unsigned short* xr2 = (unsigned short*)(ws + o_xr2);
  int* offp  = (int*)(ws + o_off);
  int* curp  = (int*)(ws + o_cur);
  int* degp  = (int*)(ws + o_deg);
  int* esrc  = (int*)(ws + o_esrc);
  float* stats = (float*)(ws + o_stats);
  float* beff1 = (float*)(ws + o_beff1);
  float* beff2 = (float*)(ws + o_beff2);
  int* btot  = (int*)(ws + o_btot);
  int* gbase = (int*)(ws + o_gbase);

  const int* src_raw = ei;
  const int* dst_raw = ei + ERAW;
  float* mu = (float*)d_out;

  cast_x_kernel<<<(MPAD * 96) / 256, 256, 0, stream>>>(x, xb, degp, stats, beff1);
  weff_kernel<<<dim3(32, 8), 256, 0, stream>>>(conv_w, conv_b, W1l, b1l, W1r, b1r, wc1, beff1);

  hist_kernel<<<(ERAW + 255) / 256, 256, 0, stream>>>(dst_raw, degp, ERAW);
  const int NB = (NN + 1023) / 1024;  // 20
  scan1_kernel<<<NB, 1024, 0, stream>>>(degp, offp, btot, NN);
  scan2_kernel<<<1, 64, 0, stream>>>(btot, gbase, offp, NB, NN);
  scan3_kernel<<<NB, 1024, 0, stream>>>(offp, curp, gbase, esrc, NN);
  scatter_kernel<<<(ERAW + 255) / 256, 256, 0, stream>>>(src_raw, dst_raw, curp, esrc, ERAW);

  // layer 1: xl1/xr1 = xb @ Weff + beff1   (conv folded in; K=768)
  gemm_kernel<unsigned short><<<(MPAD / 128) * (1024 / 128), 256, 0, stream>>>(
      xb, wc1, beff1, beff1 + 512, xl1, xr1, NN, 768, 8, 512, 1);
  // grid covers MPAD rows: pad nodes write zero h1 rows (GEMM2 A pad)
  gat_agg_kernel<8, unsigned short><<<MPAD / 4, 256, 0, stream>>>(
      xl1, xr1, att1, bias1, offp, esrc, h1, NN, 1);

  // batchnorm stats + fold into W2
  bn_stats_kernel<<<(NN + 63) / 64, 256, 0, stream>>>(h1, stats, NN);
  w2fold_kernel<<<256, 256, 0, stream>>>(stats, gamma, beta, W2l, b2l, W2r, b2r, wc2, beff2);

  // layer 2: xl2/xr2 = h1 @ W2eff + beff2  (BN folded in; K=512)
  gemm_kernel<unsigned short><<<(MPAD / 128) * (256 / 128), 256, 0, stream>>>(
      h1, wc2, beff2, beff2 + 128, xl2, xr2, NN, 512, 2, 128, 0);
  gat_agg_kernel<2, float><<<NN / 4, 256, 0, stream>>>(
      xl2, xr2, att2, bias2, offp, esrc, mu, NN, 0);
}